// Round 12
// baseline (736.210 us; speedup 1.0000x reference)
//
#include <hip/hip_runtime.h>
#include <hip/hip_bf16.h>

#define D 128
#define SEGS 256      // binscatter grid size == build_csr blockDim (segment <-> thread mapping)
#define TILE 1024     // edge tile (4 x 256); tiles round-robin across blocks -> per-(block,bin)
                      // load is graph-MIXED: worst lambda ~5 (R10 bug: contiguous chunks gave
                      // graph-LOCAL lambda ~20 for touch -> mass segment overflow -> 9.7ms scan)
#define CAP_SEG 32    // P(Poisson(5) > 32) ~ 1e-9 per cell; ovf fallback exact
#define CSRB 8192     // CSR capacity per bin = SEGS*CAP_SEG -> bin overflow structurally impossible
#define MAXBINS 4096  // LDS bin-counter capacity (harness: ~1955 bins)

typedef __attribute__((ext_vector_type(8))) short bf16x8;
typedef __attribute__((ext_vector_type(4))) float f32x4;

__device__ __forceinline__ void atomAddF(float* p, float v) { unsafeAtomicAdd(p, v); }

__device__ __forceinline__ unsigned short f2bf(float f) {
    __hip_bfloat16 h = __float2bfloat16(f);
    return *reinterpret_cast<unsigned short*>(&h);
}
__device__ __forceinline__ float bf2f(unsigned int u16) {
    unsigned int x = u16 << 16;
    return *reinterpret_cast<float*>(&x);
}
// acc += ab.lo_bf16 * w.lo_bf16 + ab.hi_bf16 * w.hi_bf16   (one VALU op for 2 values)
__device__ __forceinline__ void dot2bf(float& acc, unsigned int ab, unsigned int w) {
    asm("v_dot2_f32_bf16 %0, %1, %2, %0" : "+v"(acc) : "v"(ab), "v"(w));
}
// dst = (bf16(lo), bf16(hi)) packed, RNE — 1 op vs 2 software-RNE sequences
__device__ __forceinline__ unsigned int pk_bf16(float lo, float hi) {
    unsigned int r;
    asm("v_cvt_pk_bf16_f32 %0, %1, %2" : "=v"(r) : "v"(lo), "v"(hi));
    return r;
}

// ---------------- fused: weights-prep + zero-region + cast fp32->bf16 (x3) ----------------
__global__ void prep_cast_zero(const float* __restrict__ Wra, const float* __restrict__ Wrg,
                               const float* __restrict__ Wrt, const float* __restrict__ Wroot_t,
                               const float* __restrict__ Wroot_a, const float* __restrict__ Wroot_g,
                               const float* __restrict__ ba, const float* __restrict__ bg,
                               unsigned short* __restrict__ Wt_adj, unsigned short* __restrict__ Wt_g,
                               unsigned short* __restrict__ Wt_t, unsigned short* __restrict__ Wt_root_t,
                               unsigned short* __restrict__ Wt_sum, float* __restrict__ bsum,
                               unsigned int* __restrict__ zbase, long zwords,
                               const float* __restrict__ xa, long n4a,
                               const float* __restrict__ xb, long n4b,
                               const float* __restrict__ xc, long n4c,
                               unsigned short* __restrict__ oa,
                               unsigned short* __restrict__ ob,
                               unsigned short* __restrict__ oc) {
    long gid = (long)blockIdx.x * blockDim.x + threadIdx.x;
    if (gid < D * D) {
        int i = (int)gid;
        int k = i >> 7, n = i & 127;
        int ti = n * D + k;
        Wt_adj[ti]    = f2bf(Wra[i]);
        Wt_g[ti]      = f2bf(Wrg[i]);
        Wt_t[ti]      = f2bf(Wrt[i]);
        Wt_root_t[ti] = f2bf(Wroot_t[i]);
        Wt_sum[ti]    = f2bf(Wroot_a[i] + Wroot_g[i]);
        if (i < D) bsum[i] = ba[i] + bg[i];
        return;
    }
    gid -= D * D;
    if (gid < zwords) { zbase[gid] = 0u; return; }
    gid -= zwords;
    const float* in; unsigned short* out; long li;
    if (gid < n4a)                 { in = xa; out = oa; li = gid; }
    else if (gid < n4a + n4b)      { in = xb; out = ob; li = gid - n4a; }
    else if (gid < n4a + n4b + n4c){ in = xc; out = oc; li = gid - n4a - n4b; }
    else return;
    float4 v = ((const float4*)in)[li];
    ushort4 o;
    o.x = f2bf(v.x); o.y = f2bf(v.y); o.z = f2bf(v.z); o.w = f2bf(v.w);
    ((ushort4*)out)[li] = o;
}

// ---------------- pass 1: single-pass private-segment binning, tile-interleaved ----------------
__launch_bounds__(256)
__global__ void binscatter3(const int* __restrict__ s0, const int* __restrict__ d0, int E0,
                            const int* __restrict__ s1, const int* __restrict__ d1, int E1,
                            const int* __restrict__ s2, const int* __restrict__ d2, int E2,
                            int nbV, int totBins,
                            unsigned int* __restrict__ pairs, int* __restrict__ segcnt,
                            int* __restrict__ o0, int* __restrict__ o1, int* __restrict__ o2,
                            int* __restrict__ ovf_cnt) {
    __shared__ int lb[MAXBINS];
    const int t = threadIdx.x;
    const long Etot = (long)E0 + E1 + E2;
    const long nTiles = (Etot + TILE - 1) / TILE;

    for (int b = t; b < totBins; b += 256) lb[b] = 0;
    __syncthreads();

    const long segBase = (long)blockIdx.x * totBins;
    for (long tile = blockIdx.x; tile < nTiles; tile += SEGS) {
        const long tbase = tile * TILE;
#pragma unroll
        for (int u = 0; u < 4; ++u) {               // 4 independent edge loads in flight
            long e = tbase + (long)u * 256 + t;
            if (e >= Etot) break;
            int s, d, le, bidx, g;
            if (e < E0)                 { le = (int)e;             s = s0[le]; d = d0[le]; bidx = (d >> 8);           g = 0; }
            else if (e < (long)E0 + E1) { le = (int)(e - E0);      s = s1[le]; d = d1[le]; bidx = nbV + (d >> 8);     g = 1; }
            else                        { le = (int)(e - E0 - E1); s = s2[le]; d = d2[le]; bidx = 2 * nbV + (d >> 8); g = 2; }
            int slot = atomicAdd(&lb[bidx], 1);     // LDS cursor
            if (slot < CAP_SEG)
                pairs[(segBase + bidx) * CAP_SEG + slot] = ((unsigned int)s << 8) | (unsigned int)(d & 255);
            else {
                int* ovf = (g == 0) ? o0 : ((g == 1) ? o1 : o2);
                ovf[atomicAdd(&ovf_cnt[g * 16], 1)] = le;   // exact fallback, ~never
            }
        }
    }
    __syncthreads();
    for (int b = t; b < totBins; b += 256) {
        int c = lb[b];
        segcnt[segBase + b] = (c > CAP_SEG) ? CAP_SEG : c;
    }
}

// ---------------- pass 2: per-bin CSR build from 256 segments (thread t <-> segment t) ----------------
__launch_bounds__(256)
__global__ void build_csr(int nbV, int Nvar, int Ncon, int totBins,
                          const unsigned int* __restrict__ pairs, const int* __restrict__ segcnt,
                          unsigned int* __restrict__ csr, unsigned int* __restrict__ rowinfo) {
    const int b = blockIdx.x;
    int N, dstBase, infoBase;
    if (b < nbV)          { N = Nvar; dstBase = b * 256;             infoBase = 0; }
    else if (b < 2 * nbV) { N = Nvar; dstBase = (b - nbV) * 256;     infoBase = Nvar; }
    else                  { N = Ncon; dstBase = (b - 2 * nbV) * 256; infoBase = 2 * Nvar; }

    __shared__ int hist[256], scan[256], cur[256];
    const int t = threadIdx.x;
    const long segBase = ((long)t * totBins + b) * CAP_SEG;   // thread t's segment of this bin
    const int sc = segcnt[(long)t * totBins + b];

    hist[t] = 0;
    __syncthreads();
    for (int i = 0; i < sc; ++i) atomicAdd(&hist[pairs[segBase + i] & 255], 1);
    __syncthreads();
    scan[t] = hist[t];
    __syncthreads();
    for (int off = 1; off < 256; off <<= 1) {
        int u = (t >= off) ? scan[t - off] : 0;
        __syncthreads();
        scan[t] += u;
        __syncthreads();
    }
    const int excl = scan[t] - hist[t];
    cur[t] = excl;
    if (dstBase + t < N)
        rowinfo[infoBase + dstBase + t] = ((unsigned int)excl << 16) | (unsigned int)hist[t];
    __syncthreads();
    for (int i = 0; i < sc; ++i) {
        unsigned int pr = pairs[segBase + i];
        int slot = atomicAdd(&cur[pr & 255], 1);   // LDS atomic
        csr[(long)b * CSRB + slot] = pr >> 8;      // src index; slot < SEGS*CAP_SEG = CSRB always
    }
}

// ---------------- pass 3: pull-aggregate from CSR — 4 dst rows per wave ----------------
__launch_bounds__(256)
__global__ void pull_csr3(int Nvar, int Ncon, int nbV,
                          const unsigned short* __restrict__ xv, const unsigned short* __restrict__ xr,
                          const unsigned int* __restrict__ csr, const unsigned int* __restrict__ rowinfo,
                          const int* __restrict__ s0, const int* __restrict__ d0, const int* __restrict__ o0,
                          const int* __restrict__ s1, const int* __restrict__ d1, const int* __restrict__ o1,
                          const int* __restrict__ s2, const int* __restrict__ d2, const int* __restrict__ o2,
                          const int* __restrict__ ovf_cnt,
                          unsigned short* __restrict__ agg_adj, unsigned short* __restrict__ agg_g,
                          unsigned short* __restrict__ agg_t) {
    const int tx = threadIdx.x;
    const int lane = tx & 63;
    const int ql = lane & 15;            // column group: cols [ql*8 .. ql*8+7]
    const int sl = lane & 48;            // quarter base lane (q*16)
    const long colOff = (long)ql * 8;

    const long tot = 2L * Nvar + Ncon;
    const long wv = ((long)blockIdx.x * blockDim.x + tx) >> 6;
    long r = wv * 4 + (lane >> 4);       // this quarter's dst row (global id)
    const bool active = r < tot;
    if (!active) r = tot - 1;            // clamp for safe addressing; store guarded

    // per-lane graph selection (uniform within quarter)
    const bool g1 = (r >= Nvar) && (r < 2L * Nvar);
    const bool g2 = (r >= 2L * Nvar);
    const unsigned short* y = g1 ? xr : xv;
    const int wid = (int)(r - (g1 ? (long)Nvar : 0) - (g2 ? 2L * Nvar : 0));
    const int infoBase = g1 ? Nvar : (g2 ? 2 * Nvar : 0);
    const long binBase = g1 ? nbV : (g2 ? 2L * nbV : 0);
    unsigned short* agg = g1 ? agg_g : (g2 ? agg_t : agg_adj);

    const unsigned int info = rowinfo[infoBase + wid];
    const int mc = active ? (int)(info & 0xffffu) : 0;
    const long b = binBase + (wid >> 8);
    const long cbase = b * CSRB + (long)(info >> 16);

    float a0 = 0.f, a1 = 0.f, a2 = 0.f, a3 = 0.f, a4 = 0.f, a5 = 0.f, a6 = 0.f, a7 = 0.f;

    for (int base = 0; __any(base < mc); base += 16) {
        int idx = (base + ql < mc) ? (int)csr[cbase + base + ql] : 0;
        for (int jj = 0; jj < 16; jj += 4) {
            const int e = base + jj;
            if (!__any(e < mc)) break;
            int i0 = __shfl(idx, sl + jj + 0, 64);   // edge e of OWN quarter's row
            int i1 = __shfl(idx, sl + jj + 1, 64);
            int i2 = __shfl(idx, sl + jj + 2, 64);
            int i3 = __shfl(idx, sl + jj + 3, 64);
            uint4 r0 = *(const uint4*)(y + (long)i0 * D + colOff);
            uint4 r1 = *(const uint4*)(y + (long)i1 * D + colOff);
            uint4 r2 = *(const uint4*)(y + (long)i2 * D + colOff);
            uint4 r3 = *(const uint4*)(y + (long)i3 * D + colOff);
            unsigned int w01 = ((e     < mc) ? 0x3F80u : 0u) | ((e + 1 < mc) ? 0x3F800000u : 0u);
            unsigned int w23 = ((e + 2 < mc) ? 0x3F80u : 0u) | ((e + 3 < mc) ? 0x3F800000u : 0u);
            unsigned int p;
            // perm 0x01000504: (src0.lo_bf16, src1.lo_bf16); 0x03020706: high halves
            p = __builtin_amdgcn_perm(r0.x, r1.x, 0x01000504u); dot2bf(a0, p, w01);
            p = __builtin_amdgcn_perm(r2.x, r3.x, 0x01000504u); dot2bf(a0, p, w23);
            p = __builtin_amdgcn_perm(r0.x, r1.x, 0x03020706u); dot2bf(a1, p, w01);
            p = __builtin_amdgcn_perm(r2.x, r3.x, 0x03020706u); dot2bf(a1, p, w23);
            p = __builtin_amdgcn_perm(r0.y, r1.y, 0x01000504u); dot2bf(a2, p, w01);
            p = __builtin_amdgcn_perm(r2.y, r3.y, 0x01000504u); dot2bf(a2, p, w23);
            p = __builtin_amdgcn_perm(r0.y, r1.y, 0x03020706u); dot2bf(a3, p, w01);
            p = __builtin_amdgcn_perm(r2.y, r3.y, 0x03020706u); dot2bf(a3, p, w23);
            p = __builtin_amdgcn_perm(r0.z, r1.z, 0x01000504u); dot2bf(a4, p, w01);
            p = __builtin_amdgcn_perm(r2.z, r3.z, 0x01000504u); dot2bf(a4, p, w23);
            p = __builtin_amdgcn_perm(r0.z, r1.z, 0x03020706u); dot2bf(a5, p, w01);
            p = __builtin_amdgcn_perm(r2.z, r3.z, 0x03020706u); dot2bf(a5, p, w23);
            p = __builtin_amdgcn_perm(r0.w, r1.w, 0x01000504u); dot2bf(a6, p, w01);
            p = __builtin_amdgcn_perm(r2.w, r3.w, 0x01000504u); dot2bf(a6, p, w23);
            p = __builtin_amdgcn_perm(r0.w, r1.w, 0x03020706u); dot2bf(a7, p, w01);
            p = __builtin_amdgcn_perm(r2.w, r3.w, 0x03020706u); dot2bf(a7, p, w23);
        }
    }

    // rare exact fallback: only if some edge of this graph overflowed its segment
    const int oc = ovf_cnt[g1 ? 16 : (g2 ? 32 : 0)];
    if (active && oc > 0) {
        const int* srcp = g1 ? s1 : (g2 ? s2 : s0);
        const int* dstp = g1 ? d1 : (g2 ? d2 : d0);
        const int* ovf  = g1 ? o1 : (g2 ? o2 : o0);
        for (int i = 0; i < oc; ++i) {
            int e = ovf[i];
            if (dstp[e] == wid) {        // every lane of the quarter adds its own cols
                int s = srcp[e];
                uint4 rr = *(const uint4*)(y + (long)s * D + colOff);
                a0 += bf2f(rr.x & 0xffffu); a1 += bf2f(rr.x >> 16);
                a2 += bf2f(rr.y & 0xffffu); a3 += bf2f(rr.y >> 16);
                a4 += bf2f(rr.z & 0xffffu); a5 += bf2f(rr.z >> 16);
                a6 += bf2f(rr.w & 0xffffu); a7 += bf2f(rr.w >> 16);
            }
        }
    }

    if (active) {
        uint4 o;
        o.x = pk_bf16(a0, a1);
        o.y = pk_bf16(a2, a3);
        o.z = pk_bf16(a4, a5);
        o.w = pk_bf16(a6, a7);
        *(uint4*)(agg + (long)wid * D + colOff) = o;
    }
}

// ---------------- fused MFMA GEMM, LDS-staged (m97-style 2-phase), var+con MERGED ----------------
// Inner pipeline is R2-verbatim (__syncthreads double-buffer; proven 96us shape).
// Only change: var blocks [0,nbVar) run 3 terms, con blocks [nbVar,nbVar+nbCon) run 2 —
// con fills the var tail and one launch gap disappears. R3 proved the merge itself keeps
// write traffic at logical (152MB); R4's blowup correlated with raw-barrier scheduling,
// which is NOT used here. Falsifier: WRITE >> 152MB -> revert merge.
__launch_bounds__(256, 4)
__global__ void gemm_fused(int nbVar, int Nvar, int Ncon,
                           const unsigned short* __restrict__ Av0, const unsigned short* __restrict__ Wv0,
                           const unsigned short* __restrict__ Av1, const unsigned short* __restrict__ Wv1,
                           const unsigned short* __restrict__ Av2, const unsigned short* __restrict__ Wv2,
                           const unsigned short* __restrict__ Ac0, const unsigned short* __restrict__ Wc0,
                           const unsigned short* __restrict__ Ac1, const unsigned short* __restrict__ Wc1,
                           const float* __restrict__ biasV, const float* __restrict__ biasC,
                           float* __restrict__ outV, float* __restrict__ outC,
                           float* __restrict__ stats) {
    __shared__ unsigned short lds[2][8192];   // per buf: A slots 0..511 (8KB), B slots at +4096 (8KB)
    __shared__ float sstat[256];
    const int tx = threadIdx.x;
    sstat[tx] = 0.f;                          // visible after first __syncthreads below

    const bool isVar = (int)blockIdx.x < nbVar;
    const int bid = isVar ? (int)blockIdx.x : (int)blockIdx.x - nbVar;
    const int N = isVar ? Nvar : Ncon;
    const float* bias = isVar ? biasV : biasC;
    float* out = isVar ? outV : outC;
    float* gsum = stats + (isVar ? 0 : 256);
    float* gsq = gsum + 128;

    const int wave = tx >> 6, lane = tx & 63;
    const int quad = lane >> 4, l16 = lane & 15;
    const int row0 = bid * 128;

    const int sA0 = tx, sA1 = tx + 256;
    const int rS0 = sA0 >> 2, qS0 = (sA0 & 3) ^ ((sA0 >> 4) & 3);
    const int rS1 = sA1 >> 2, qS1 = (sA1 & 3) ^ ((sA1 >> 4) & 3);
    long gr0 = (long)row0 + rS0; if (gr0 >= N) gr0 = N - 1;   // clamp ragged tail (epilogue guards exactness)
    long gr1 = (long)row0 + rS1; if (gr1 >= N) gr1 = N - 1;

    f32x4 acc[2][8];
#pragma unroll
    for (int rt = 0; rt < 2; ++rt)
#pragma unroll
        for (int ct = 0; ct < 8; ++ct)
#pragma unroll
            for (int i = 0; i < 4; ++i) acc[rt][ct][i] = 0.f;

    auto stage = [&](int s, int bb) {
        const int t = s >> 2;
        const int k0 = (s & 3) * 32;
        const unsigned short* A = (t == 0) ? (isVar ? Av0 : Ac0)
                                : (t == 1) ? (isVar ? Av1 : Ac1) : Av2;
        const unsigned short* W = (t == 0) ? (isVar ? Wv0 : Wc0)
                                : (t == 1) ? (isVar ? Wv1 : Wc1) : Wv2;
        __builtin_amdgcn_global_load_lds(
            (const __attribute__((address_space(1))) unsigned int*)(A + gr0 * D + k0 + qS0 * 8),
            (__attribute__((address_space(3))) unsigned int*)(&lds[bb][sA0 * 8]), 16, 0, 0);
        __builtin_amdgcn_global_load_lds(
            (const __attribute__((address_space(1))) unsigned int*)(A + gr1 * D + k0 + qS1 * 8),
            (__attribute__((address_space(3))) unsigned int*)(&lds[bb][sA1 * 8]), 16, 0, 0);
        __builtin_amdgcn_global_load_lds(
            (const __attribute__((address_space(1))) unsigned int*)(W + (long)rS0 * D + k0 + qS0 * 8),
            (__attribute__((address_space(3))) unsigned int*)(&lds[bb][4096 + sA0 * 8]), 16, 0, 0);
        __builtin_amdgcn_global_load_lds(
            (const __attribute__((address_space(1))) unsigned int*)(W + (long)rS1 * D + k0 + qS1 * 8),
            (__attribute__((address_space(3))) unsigned int*)(&lds[bb][4096 + sA1 * 8]), 16, 0, 0);
    };

    const int xq = (l16 >> 2) & 3;
    const int qx = quad ^ xq;

    auto compute = [&](int cb) {
        const int slotA0 = (wave * 32 + l16) * 4 + qx;
        const int slotA1 = (wave * 32 + 16 + l16) * 4 + qx;
        bf16x8 a0 = *(const bf16x8*)&lds[cb][slotA0 * 8];
        bf16x8 a1 = *(const bf16x8*)&lds[cb][slotA1 * 8];
#pragma unroll
        for (int ct = 0; ct < 8; ++ct) {
            const int slotB = (ct * 16 + l16) * 4 + qx;
            bf16x8 b = *(const bf16x8*)&lds[cb][4096 + slotB * 8];
            acc[0][ct] = __builtin_amdgcn_mfma_f32_16x16x32_bf16(a0, b, acc[0][ct], 0, 0, 0);
            acc[1][ct] = __builtin_amdgcn_mfma_f32_16x16x32_bf16(a1, b, acc[1][ct], 0, 0, 0);
        }
    };

    const int nsteps = (isVar ? 3 : 2) * 4;
    stage(0, 0);
    __syncthreads();                      // drains vmcnt(0): buf0 ready; sstat init visible
    for (int s = 0; s < nsteps; ++s) {
        const int cb = s & 1;
        if (s + 1 < nsteps) stage(s + 1, cb ^ 1);   // issue prefetch BEFORE compute
        compute(cb);
        __syncthreads();                  // next buf staged + this buf free for overwrite
    }

    // epilogue: bias, store, per-column partial stats
    float bv[8];
#pragma unroll
    for (int ct = 0; ct < 8; ++ct) bv[ct] = bias[ct * 16 + l16];

    float psum[8], psq[8];
#pragma unroll
    for (int ct = 0; ct < 8; ++ct) { psum[ct] = 0.f; psq[ct] = 0.f; }

#pragma unroll
    for (int rt = 0; rt < 2; ++rt)
#pragma unroll
        for (int i = 0; i < 4; ++i) {
            int row = row0 + wave * 32 + rt * 16 + quad * 4 + i;
            if (row < N) {
#pragma unroll
                for (int ct = 0; ct < 8; ++ct) {
                    float v = acc[rt][ct][i] + bv[ct];
                    out[(size_t)row * D + ct * 16 + l16] = v;
                    psum[ct] += v;
                    psq[ct] += v * v;
                }
            }
        }

#pragma unroll
    for (int ct = 0; ct < 8; ++ct) {
        atomicAdd(&sstat[ct * 16 + l16], psum[ct]);
        atomicAdd(&sstat[128 + ct * 16 + l16], psq[ct]);
    }
    __syncthreads();
    if (tx < 128) {
        atomAddF(&gsum[tx], sstat[tx]);
        atomAddF(&gsq[tx], sstat[128 + tx]);
    }
}

// ---------------- fused normalize+relu with per-block stats finalization ----------------
__global__ void norm_relu_fin(float* __restrict__ buf,
                              long nvecVar, long nvecTot,
                              const float* __restrict__ stats,
                              const float* __restrict__ wv, const float* __restrict__ bv, const float* __restrict__ msv,
                              const float* __restrict__ wc, const float* __restrict__ bc, const float* __restrict__ msc,
                              int Nvar, int Ncon) {
    __shared__ float ss[512];   // [0:128) scale_var [128:256) shift_var [256:384) scale_con [384:512) shift_con
    const int t = threadIdx.x;
    {
        const int col = t & 127;
        const bool isv = t < 128;
        const float n = isv ? (float)Nvar : (float)Ncon;
        const float* st = stats + (isv ? 0 : 256);
        const float mu = st[col] / n;
        const float ex2 = st[128 + col] / n;
        const float ms = (isv ? msv : msc)[col];
        const float var = ex2 - 2.f * ms * mu * mu + ms * ms * mu * mu;
        const float istd = rsqrtf(var + 1e-5f);
        const float sc = (isv ? wv : wc)[col] * istd;
        ss[(isv ? 0 : 256) + col] = sc;
        ss[(isv ? 128 : 384) + col] = (isv ? bv : bc)[col] - sc * ms * mu;
    }
    __syncthreads();
    long i = (long)blockIdx.x * blockDim.x + t;
    if (i >= nvecTot) return;
    const int base = (i < nvecVar) ? 0 : 256;
    const int q = ((int)i & 31) * 4;
    float4 v = *(float4*)(buf + i * 4);
    float4 o;
    o.x = fmaxf(0.f, v.x * ss[base + q + 0] + ss[base + 128 + q + 0]);
    o.y = fmaxf(0.f, v.y * ss[base + q + 1] + ss[base + 128 + q + 1]);
    o.z = fmaxf(0.f, v.z * ss[base + q + 2] + ss[base + 128 + q + 2]);
    o.w = fmaxf(0.f, v.w * ss[base + q + 3] + ss[base + 128 + q + 3]);
    *(float4*)(buf + i * 4) = o;
}

extern "C" void kernel_launch(void* const* d_in, const int* in_sizes, int n_in,
                              void* d_out, int out_size, void* d_ws, size_t ws_size,
                              hipStream_t stream) {
    const float* x_var = (const float*)d_in[0];
    const float* x_con = (const float*)d_in[1];
    const float* x_reg = (const float*)d_in[2];
    const int* src_adj = (const int*)d_in[3];
    const int* dst_adj = (const int*)d_in[4];
    const int* src_t   = (const int*)d_in[5];
    const int* dst_t   = (const int*)d_in[6];
    const int* src_g   = (const int*)d_in[7];
    const int* dst_g   = (const int*)d_in[8];
    const float* W_rel_adj  = (const float*)d_in[9];
    const float* b_adj      = (const float*)d_in[10];
    const float* W_root_adj = (const float*)d_in[11];
    const float* W_rel_t    = (const float*)d_in[12];
    const float* b_t        = (const float*)d_in[13];
    const float* W_root_t   = (const float*)d_in[14];
    const float* W_rel_g    = (const float*)d_in[15];
    const float* b_g        = (const float*)d_in[16];
    const float* W_root_g   = (const float*)d_in[17];
    const float* gnw_v  = (const float*)d_in[18];
    const float* gnb_v  = (const float*)d_in[19];
    const float* gnms_v = (const float*)d_in[20];
    const float* gnw_c  = (const float*)d_in[21];
    const float* gnb_c  = (const float*)d_in[22];
    const float* gnms_c = (const float*)d_in[23];

    const int Nvar = in_sizes[0] / D;
    const int Ncon = in_sizes[1] / D;
    const int Nreg = in_sizes[2] / D;
    const int Eadj = in_sizes[3];
    const int Et   = in_sizes[5];
    const int Eg   = in_sizes[7];

    const int nbV = (Nvar + 255) >> 8;     // bins per var-dst graph (adj, groups)
    const int nbC = (Ncon + 255) >> 8;     // bins for touch
    const int totBins = 2 * nbV + nbC;

    // ---- workspace layout (large blocks first, all 256B-aligned) ----
    char* p = (char*)d_ws;
    unsigned short* xv_bf = (unsigned short*)p; p += (size_t)Nvar * D * 2;
    unsigned short* xc_bf = (unsigned short*)p; p += (size_t)Ncon * D * 2;
    unsigned short* xr_bf = (unsigned short*)p; p += (size_t)Nreg * D * 2;
    unsigned short* agg_adj = (unsigned short*)p; p += (size_t)Nvar * D * 2;
    unsigned short* agg_g   = (unsigned short*)p; p += (size_t)Nvar * D * 2;
    unsigned short* agg_t   = (unsigned short*)p; p += (size_t)Ncon * D * 2;
    unsigned int* pairs = (unsigned int*)p; p += (size_t)SEGS * totBins * CAP_SEG * 4;
    unsigned int* csr   = (unsigned int*)p; p += (size_t)totBins * CSRB * 4;
    int* segcnt = (int*)p; p += (size_t)SEGS * totBins * 4;
    unsigned int* rowinfo = (unsigned int*)p; p += (size_t)(2 * Nvar + Ncon) * 4;
    int* ovf0 = (int*)p; p += (size_t)Eadj * 4;
    int* ovf1 = (int*)p; p += (size_t)Eg * 4;
    int* ovf2 = (int*)p; p += (size_t)Et * 4;
    unsigned short* Wt_adj    = (unsigned short*)p; p += D * D * 2;
    unsigned short* Wt_g      = (unsigned short*)p; p += D * D * 2;
    unsigned short* Wt_t      = (unsigned short*)p; p += D * D * 2;
    unsigned short* Wt_root_t = (unsigned short*)p; p += D * D * 2;
    unsigned short* Wt_sum    = (unsigned short*)p; p += D * D * 2;
    float* bsum  = (float*)p; p += D * 4;
    // ---- contiguous zero region: stats(512f) + ovf_cnt(64i) ----
    char* zbase = p;
    float* stats   = (float*)p; p += 512 * 4;
    int* ovf_cnt   = (int*)p;   p += 64 * 4;         // [0],[16],[32] used
    const long zwords = (long)(p - zbase) / 4;

    float* out_var = (float*)d_out;
    float* out_con = out_var + (size_t)Nvar * D;

    // 1: fused weights-prep + zero + casts
    {
        long n4v = (long)Nvar * 32, n4c = (long)Ncon * 32, n4r = (long)Nreg * 32;
        long tot = (long)D * D + zwords + n4v + n4c + n4r;
        prep_cast_zero<<<(int)((tot + 255) / 256), 256, 0, stream>>>(
            W_rel_adj, W_rel_g, W_rel_t, W_root_t, W_root_adj, W_root_g, b_adj, b_g,
            Wt_adj, Wt_g, Wt_t, Wt_root_t, Wt_sum, bsum,
            (unsigned int*)zbase, zwords,
            x_var, n4v, x_con, n4c, x_reg, n4r, xv_bf, xc_bf, xr_bf);
    }

    // 2: single-pass private-segment binning, tile-interleaved (grid MUST be SEGS)
    binscatter3<<<SEGS, 256, 0, stream>>>(
        src_adj, dst_adj, Eadj,
        src_g,   dst_g,   Eg,
        src_t,   dst_t,   Et,
        nbV, totBins, pairs, segcnt, ovf0, ovf1, ovf2, ovf_cnt);

    // 3: per-bin CSR build (blockDim MUST be SEGS)
    build_csr<<<totBins, SEGS, 0, stream>>>(nbV, Nvar, Ncon, totBins, pairs, segcnt, csr, rowinfo);

    // 4: pull-aggregate from CSR (4 rows per wave)
    {
        long rows = (long)2 * Nvar + Ncon;
        long T = ((rows + 3) / 4) * 64;
        pull_csr3<<<(int)((T + 255) / 256), 256, 0, stream>>>(
            Nvar, Ncon, nbV, xv_bf, xr_bf,
            csr, rowinfo,
            src_adj, dst_adj, ovf0,
            src_g,   dst_g,   ovf1,
            src_t,   dst_t,   ovf2,
            ovf_cnt, agg_adj, agg_g, agg_t);
    }

    // 5: merged GEMM (var blocks first, con blocks fill the tail)
    {
        const int nbVar = (Nvar + 127) / 128;
        const int nbCon = (Ncon + 127) / 128;
        gemm_fused<<<nbVar + nbCon, 256, 0, stream>>>(nbVar, Nvar, Ncon,
            agg_adj, Wt_adj, agg_g, Wt_g, xv_bf, Wt_sum,
            agg_t, Wt_t, xc_bf, Wt_root_t,
            bsum, b_t, out_var, out_con, stats);
    }

    // 6: fused normalize+relu+finalize over the contiguous [out_var | out_con] buffer
    {
        long nvecVar = (long)Nvar * 32;
        long nvecTot = (long)(Nvar + Ncon) * 32;
        norm_relu_fin<<<(int)((nvecTot + 255) / 256), 256, 0, stream>>>(
            out_var, nvecVar, nvecTot, stats,
            gnw_v, gnb_v, gnms_v, gnw_c, gnb_c, gnms_c, Nvar, Ncon);
    }
}

// Round 13
// 677.125 us; speedup vs baseline: 1.0873x; 1.0873x over previous
//
#include <hip/hip_runtime.h>
#include <hip/hip_bf16.h>

#define D 128
#define SEGS 256      // binscatter grid size == build_csr blockDim (segment <-> thread mapping)
#define TILE 1024     // edge tile (4 x 256); tiles round-robin across blocks -> per-(block,bin)
                      // load is graph-MIXED: worst lambda ~5 (R10 lesson: contiguous chunks gave
                      // graph-LOCAL lambda ~20 for touch -> mass segment overflow -> 9.7ms scan)
#define CAP_SEG 32    // P(Poisson(5) > 32) ~ 1e-9 per cell; ovf fallback exact
#define CSRB 8192     // CSR capacity per bin = SEGS*CAP_SEG -> bin overflow structurally impossible
#define MAXBINS 4096  // LDS bin-counter capacity (harness: ~1955 bins)

// pairs layout is [bin][seg][slot] (R13 transpose): binscatter writes 128B-contiguous
// per (bin,seg) cell sequentially (L2 write-combine; 250KB/block footprint), build_csr
// block b reads one contiguous 32KB region. R12's [seg][bin][slot] made build_csr
// threads stride 250KB apart -> every 4B read was its own line (~160MB effective).

typedef __attribute__((ext_vector_type(8))) short bf16x8;
typedef __attribute__((ext_vector_type(4))) float f32x4;

__device__ __forceinline__ void atomAddF(float* p, float v) { unsafeAtomicAdd(p, v); }

__device__ __forceinline__ unsigned short f2bf(float f) {
    __hip_bfloat16 h = __float2bfloat16(f);
    return *reinterpret_cast<unsigned short*>(&h);
}
__device__ __forceinline__ float bf2f(unsigned int u16) {
    unsigned int x = u16 << 16;
    return *reinterpret_cast<float*>(&x);
}
// acc += ab.lo_bf16 * w.lo_bf16 + ab.hi_bf16 * w.hi_bf16   (one VALU op for 2 values)
__device__ __forceinline__ void dot2bf(float& acc, unsigned int ab, unsigned int w) {
    asm("v_dot2_f32_bf16 %0, %1, %2, %0" : "+v"(acc) : "v"(ab), "v"(w));
}
// dst = (bf16(lo), bf16(hi)) packed, RNE — 1 op vs 2 software-RNE sequences
__device__ __forceinline__ unsigned int pk_bf16(float lo, float hi) {
    unsigned int r;
    asm("v_cvt_pk_bf16_f32 %0, %1, %2" : "=v"(r) : "v"(lo), "v"(hi));
    return r;
}

// ---------------- fused: weights-prep + zero-region + cast fp32->bf16 (x3) ----------------
__global__ void prep_cast_zero(const float* __restrict__ Wra, const float* __restrict__ Wrg,
                               const float* __restrict__ Wrt, const float* __restrict__ Wroot_t,
                               const float* __restrict__ Wroot_a, const float* __restrict__ Wroot_g,
                               const float* __restrict__ ba, const float* __restrict__ bg,
                               unsigned short* __restrict__ Wt_adj, unsigned short* __restrict__ Wt_g,
                               unsigned short* __restrict__ Wt_t, unsigned short* __restrict__ Wt_root_t,
                               unsigned short* __restrict__ Wt_sum, float* __restrict__ bsum,
                               unsigned int* __restrict__ zbase, long zwords,
                               const float* __restrict__ xa, long n4a,
                               const float* __restrict__ xb, long n4b,
                               const float* __restrict__ xc, long n4c,
                               unsigned short* __restrict__ oa,
                               unsigned short* __restrict__ ob,
                               unsigned short* __restrict__ oc) {
    long gid = (long)blockIdx.x * blockDim.x + threadIdx.x;
    if (gid < D * D) {
        int i = (int)gid;
        int k = i >> 7, n = i & 127;
        int ti = n * D + k;
        Wt_adj[ti]    = f2bf(Wra[i]);
        Wt_g[ti]      = f2bf(Wrg[i]);
        Wt_t[ti]      = f2bf(Wrt[i]);
        Wt_root_t[ti] = f2bf(Wroot_t[i]);
        Wt_sum[ti]    = f2bf(Wroot_a[i] + Wroot_g[i]);
        if (i < D) bsum[i] = ba[i] + bg[i];
        return;
    }
    gid -= D * D;
    if (gid < zwords) { zbase[gid] = 0u; return; }
    gid -= zwords;
    const float* in; unsigned short* out; long li;
    if (gid < n4a)                 { in = xa; out = oa; li = gid; }
    else if (gid < n4a + n4b)      { in = xb; out = ob; li = gid - n4a; }
    else if (gid < n4a + n4b + n4c){ in = xc; out = oc; li = gid - n4a - n4b; }
    else return;
    float4 v = ((const float4*)in)[li];
    ushort4 o;
    o.x = f2bf(v.x); o.y = f2bf(v.y); o.z = f2bf(v.z); o.w = f2bf(v.w);
    ((ushort4*)out)[li] = o;
}

// ---------------- pass 1: single-pass private-segment binning, tile-interleaved ----------------
__launch_bounds__(256)
__global__ void binscatter3(const int* __restrict__ s0, const int* __restrict__ d0, int E0,
                            const int* __restrict__ s1, const int* __restrict__ d1, int E1,
                            const int* __restrict__ s2, const int* __restrict__ d2, int E2,
                            int nbV, int totBins,
                            unsigned int* __restrict__ pairs, int* __restrict__ segcnt,
                            int* __restrict__ o0, int* __restrict__ o1, int* __restrict__ o2,
                            int* __restrict__ ovf_cnt) {
    __shared__ int lb[MAXBINS];
    const int t = threadIdx.x;
    const long Etot = (long)E0 + E1 + E2;
    const long nTiles = (Etot + TILE - 1) / TILE;

    for (int b = t; b < totBins; b += 256) lb[b] = 0;
    __syncthreads();

    const int seg = blockIdx.x;
    for (long tile = seg; tile < nTiles; tile += SEGS) {
        const long tbase = tile * TILE;
#pragma unroll
        for (int u = 0; u < 4; ++u) {               // 4 independent edge loads in flight
            long e = tbase + (long)u * 256 + t;
            if (e >= Etot) break;
            int s, d, le, bidx, g;
            if (e < E0)                 { le = (int)e;             s = s0[le]; d = d0[le]; bidx = (d >> 8);           g = 0; }
            else if (e < (long)E0 + E1) { le = (int)(e - E0);      s = s1[le]; d = d1[le]; bidx = nbV + (d >> 8);     g = 1; }
            else                        { le = (int)(e - E0 - E1); s = s2[le]; d = d2[le]; bidx = 2 * nbV + (d >> 8); g = 2; }
            int slot = atomicAdd(&lb[bidx], 1);     // LDS cursor
            if (slot < CAP_SEG)
                pairs[((long)bidx * SEGS + seg) * CAP_SEG + slot] = ((unsigned int)s << 8) | (unsigned int)(d & 255);
            else {
                int* ovf = (g == 0) ? o0 : ((g == 1) ? o1 : o2);
                ovf[atomicAdd(&ovf_cnt[g * 16], 1)] = le;   // exact fallback, ~never
            }
        }
    }
    __syncthreads();
    for (int b = t; b < totBins; b += 256) {
        int c = lb[b];
        segcnt[(long)b * SEGS + seg] = (c > CAP_SEG) ? CAP_SEG : c;
    }
}

// ---------------- pass 2: per-bin CSR build from 256 segments (thread t <-> segment t) ----------------
__launch_bounds__(256)
__global__ void build_csr(int nbV, int Nvar, int Ncon, int totBins,
                          const unsigned int* __restrict__ pairs, const int* __restrict__ segcnt,
                          unsigned int* __restrict__ csr, unsigned int* __restrict__ rowinfo) {
    const int b = blockIdx.x;
    int N, dstBase, infoBase;
    if (b < nbV)          { N = Nvar; dstBase = b * 256;             infoBase = 0; }
    else if (b < 2 * nbV) { N = Nvar; dstBase = (b - nbV) * 256;     infoBase = Nvar; }
    else                  { N = Ncon; dstBase = (b - 2 * nbV) * 256; infoBase = 2 * Nvar; }

    __shared__ int hist[256], scan[256], cur[256];
    const int t = threadIdx.x;
    const long segBase = ((long)b * SEGS + t) * CAP_SEG;   // thread t's segment of this bin (contiguous per block)
    const int sc = segcnt[(long)b * SEGS + t];

    hist[t] = 0;
    __syncthreads();
    for (int i = 0; i < sc; ++i) atomicAdd(&hist[pairs[segBase + i] & 255], 1);
    __syncthreads();
    scan[t] = hist[t];
    __syncthreads();
    for (int off = 1; off < 256; off <<= 1) {
        int u = (t >= off) ? scan[t - off] : 0;
        __syncthreads();
        scan[t] += u;
        __syncthreads();
    }
    const int excl = scan[t] - hist[t];
    cur[t] = excl;
    if (dstBase + t < N)
        rowinfo[infoBase + dstBase + t] = ((unsigned int)excl << 16) | (unsigned int)hist[t];
    __syncthreads();
    for (int i = 0; i < sc; ++i) {
        unsigned int pr = pairs[segBase + i];
        int slot = atomicAdd(&cur[pr & 255], 1);   // LDS atomic
        csr[(long)b * CSRB + slot] = pr >> 8;      // src index; slot < SEGS*CAP_SEG = CSRB always
    }
}

// ---------------- pass 3: pull-aggregate from CSR — 4 dst rows per wave ----------------
__launch_bounds__(256)
__global__ void pull_csr3(int Nvar, int Ncon, int nbV,
                          const unsigned short* __restrict__ xv, const unsigned short* __restrict__ xr,
                          const unsigned int* __restrict__ csr, const unsigned int* __restrict__ rowinfo,
                          const int* __restrict__ s0, const int* __restrict__ d0, const int* __restrict__ o0,
                          const int* __restrict__ s1, const int* __restrict__ d1, const int* __restrict__ o1,
                          const int* __restrict__ s2, const int* __restrict__ d2, const int* __restrict__ o2,
                          const int* __restrict__ ovf_cnt,
                          unsigned short* __restrict__ agg_adj, unsigned short* __restrict__ agg_g,
                          unsigned short* __restrict__ agg_t) {
    const int tx = threadIdx.x;
    const int lane = tx & 63;
    const int ql = lane & 15;            // column group: cols [ql*8 .. ql*8+7]
    const int sl = lane & 48;            // quarter base lane (q*16)
    const long colOff = (long)ql * 8;

    const long tot = 2L * Nvar + Ncon;
    const long wv = ((long)blockIdx.x * blockDim.x + tx) >> 6;
    long r = wv * 4 + (lane >> 4);       // this quarter's dst row (global id)
    const bool active = r < tot;
    if (!active) r = tot - 1;            // clamp for safe addressing; store guarded

    // per-lane graph selection (uniform within quarter)
    const bool g1 = (r >= Nvar) && (r < 2L * Nvar);
    const bool g2 = (r >= 2L * Nvar);
    const unsigned short* y = g1 ? xr : xv;
    const int wid = (int)(r - (g1 ? (long)Nvar : 0) - (g2 ? 2L * Nvar : 0));
    const int infoBase = g1 ? Nvar : (g2 ? 2 * Nvar : 0);
    const long binBase = g1 ? nbV : (g2 ? 2L * nbV : 0);
    unsigned short* agg = g1 ? agg_g : (g2 ? agg_t : agg_adj);

    const unsigned int info = rowinfo[infoBase + wid];
    const int mc = active ? (int)(info & 0xffffu) : 0;
    const long b = binBase + (wid >> 8);
    const long cbase = b * CSRB + (long)(info >> 16);

    float a0 = 0.f, a1 = 0.f, a2 = 0.f, a3 = 0.f, a4 = 0.f, a5 = 0.f, a6 = 0.f, a7 = 0.f;

    for (int base = 0; __any(base < mc); base += 16) {
        int idx = (base + ql < mc) ? (int)csr[cbase + base + ql] : 0;
        for (int jj = 0; jj < 16; jj += 4) {
            const int e = base + jj;
            if (!__any(e < mc)) break;
            int i0 = __shfl(idx, sl + jj + 0, 64);   // edge e of OWN quarter's row
            int i1 = __shfl(idx, sl + jj + 1, 64);
            int i2 = __shfl(idx, sl + jj + 2, 64);
            int i3 = __shfl(idx, sl + jj + 3, 64);
            uint4 r0 = *(const uint4*)(y + (long)i0 * D + colOff);
            uint4 r1 = *(const uint4*)(y + (long)i1 * D + colOff);
            uint4 r2 = *(const uint4*)(y + (long)i2 * D + colOff);
            uint4 r3 = *(const uint4*)(y + (long)i3 * D + colOff);
            unsigned int w01 = ((e     < mc) ? 0x3F80u : 0u) | ((e + 1 < mc) ? 0x3F800000u : 0u);
            unsigned int w23 = ((e + 2 < mc) ? 0x3F80u : 0u) | ((e + 3 < mc) ? 0x3F800000u : 0u);
            unsigned int p;
            // perm 0x01000504: (src0.lo_bf16, src1.lo_bf16); 0x03020706: high halves
            p = __builtin_amdgcn_perm(r0.x, r1.x, 0x01000504u); dot2bf(a0, p, w01);
            p = __builtin_amdgcn_perm(r2.x, r3.x, 0x01000504u); dot2bf(a0, p, w23);
            p = __builtin_amdgcn_perm(r0.x, r1.x, 0x03020706u); dot2bf(a1, p, w01);
            p = __builtin_amdgcn_perm(r2.x, r3.x, 0x03020706u); dot2bf(a1, p, w23);
            p = __builtin_amdgcn_perm(r0.y, r1.y, 0x01000504u); dot2bf(a2, p, w01);
            p = __builtin_amdgcn_perm(r2.y, r3.y, 0x01000504u); dot2bf(a2, p, w23);
            p = __builtin_amdgcn_perm(r0.y, r1.y, 0x03020706u); dot2bf(a3, p, w01);
            p = __builtin_amdgcn_perm(r2.y, r3.y, 0x03020706u); dot2bf(a3, p, w23);
            p = __builtin_amdgcn_perm(r0.z, r1.z, 0x01000504u); dot2bf(a4, p, w01);
            p = __builtin_amdgcn_perm(r2.z, r3.z, 0x01000504u); dot2bf(a4, p, w23);
            p = __builtin_amdgcn_perm(r0.z, r1.z, 0x03020706u); dot2bf(a5, p, w01);
            p = __builtin_amdgcn_perm(r2.z, r3.z, 0x03020706u); dot2bf(a5, p, w23);
            p = __builtin_amdgcn_perm(r0.w, r1.w, 0x01000504u); dot2bf(a6, p, w01);
            p = __builtin_amdgcn_perm(r2.w, r3.w, 0x01000504u); dot2bf(a6, p, w23);
            p = __builtin_amdgcn_perm(r0.w, r1.w, 0x03020706u); dot2bf(a7, p, w01);
            p = __builtin_amdgcn_perm(r2.w, r3.w, 0x03020706u); dot2bf(a7, p, w23);
        }
    }

    // rare exact fallback: only if some edge of this graph overflowed its segment
    const int oc = ovf_cnt[g1 ? 16 : (g2 ? 32 : 0)];
    if (active && oc > 0) {
        const int* srcp = g1 ? s1 : (g2 ? s2 : s0);
        const int* dstp = g1 ? d1 : (g2 ? d2 : d0);
        const int* ovf  = g1 ? o1 : (g2 ? o2 : o0);
        for (int i = 0; i < oc; ++i) {
            int e = ovf[i];
            if (dstp[e] == wid) {        // every lane of the quarter adds its own cols
                int s = srcp[e];
                uint4 rr = *(const uint4*)(y + (long)s * D + colOff);
                a0 += bf2f(rr.x & 0xffffu); a1 += bf2f(rr.x >> 16);
                a2 += bf2f(rr.y & 0xffffu); a3 += bf2f(rr.y >> 16);
                a4 += bf2f(rr.z & 0xffffu); a5 += bf2f(rr.z >> 16);
                a6 += bf2f(rr.w & 0xffffu); a7 += bf2f(rr.w >> 16);
            }
        }
    }

    if (active) {
        uint4 o;
        o.x = pk_bf16(a0, a1);
        o.y = pk_bf16(a2, a3);
        o.z = pk_bf16(a4, a5);
        o.w = pk_bf16(a6, a7);
        *(uint4*)(agg + (long)wid * D + colOff) = o;
    }
}

// ---------------- fused MFMA GEMM, LDS-staged (m97-style 2-phase) — R2/R11-verbatim ----------------
// SPLIT var/con dispatches are REQUIRED: merging them (R4, R12) doubles HBM traffic
// (WRITE 152->314MB, FETCH 115->298MB; L3 overflow from co-resident streams) and costs +66us.
__launch_bounds__(256, 4)
__global__ void gemm_fused(int N,
                           const unsigned short* __restrict__ A0, const unsigned short* __restrict__ Wt0,
                           const unsigned short* __restrict__ A1, const unsigned short* __restrict__ Wt1,
                           const unsigned short* __restrict__ A2, const unsigned short* __restrict__ Wt2,
                           int nTerms,
                           const float* __restrict__ bias, float* __restrict__ out,
                           float* __restrict__ gsum, float* __restrict__ gsq) {
    __shared__ unsigned short lds[2][8192];   // per buf: A slots 0..511 (8KB), B slots at +4096 (8KB)
    __shared__ float sstat[256];
    const int tx = threadIdx.x;
    sstat[tx] = 0.f;

    const int wave = tx >> 6, lane = tx & 63;
    const int quad = lane >> 4, l16 = lane & 15;
    const int row0 = blockIdx.x * 128;

    const int sA0 = tx, sA1 = tx + 256;
    const int rS0 = sA0 >> 2, qS0 = (sA0 & 3) ^ ((sA0 >> 4) & 3);
    const int rS1 = sA1 >> 2, qS1 = (sA1 & 3) ^ ((sA1 >> 4) & 3);
    long gr0 = (long)row0 + rS0; if (gr0 >= N) gr0 = N - 1;
    long gr1 = (long)row0 + rS1; if (gr1 >= N) gr1 = N - 1;

    f32x4 acc[2][8];
#pragma unroll
    for (int rt = 0; rt < 2; ++rt)
#pragma unroll
        for (int ct = 0; ct < 8; ++ct)
#pragma unroll
            for (int i = 0; i < 4; ++i) acc[rt][ct][i] = 0.f;

    auto stage = [&](int s, int bb) {
        const int t = s >> 2;
        const int k0 = (s & 3) * 32;
        const unsigned short* A = (t == 0) ? A0 : ((t == 1) ? A1 : A2);
        const unsigned short* W = (t == 0) ? Wt0 : ((t == 1) ? Wt1 : Wt2);
        __builtin_amdgcn_global_load_lds(
            (const __attribute__((address_space(1))) unsigned int*)(A + gr0 * D + k0 + qS0 * 8),
            (__attribute__((address_space(3))) unsigned int*)(&lds[bb][sA0 * 8]), 16, 0, 0);
        __builtin_amdgcn_global_load_lds(
            (const __attribute__((address_space(1))) unsigned int*)(A + gr1 * D + k0 + qS1 * 8),
            (__attribute__((address_space(3))) unsigned int*)(&lds[bb][sA1 * 8]), 16, 0, 0);
        __builtin_amdgcn_global_load_lds(
            (const __attribute__((address_space(1))) unsigned int*)(W + (long)rS0 * D + k0 + qS0 * 8),
            (__attribute__((address_space(3))) unsigned int*)(&lds[bb][4096 + sA0 * 8]), 16, 0, 0);
        __builtin_amdgcn_global_load_lds(
            (const __attribute__((address_space(1))) unsigned int*)(W + (long)rS1 * D + k0 + qS1 * 8),
            (__attribute__((address_space(3))) unsigned int*)(&lds[bb][4096 + sA1 * 8]), 16, 0, 0);
    };

    const int xq = (l16 >> 2) & 3;
    const int qx = quad ^ xq;

    auto compute = [&](int cb) {
        const int slotA0 = (wave * 32 + l16) * 4 + qx;
        const int slotA1 = (wave * 32 + 16 + l16) * 4 + qx;
        bf16x8 a0 = *(const bf16x8*)&lds[cb][slotA0 * 8];
        bf16x8 a1 = *(const bf16x8*)&lds[cb][slotA1 * 8];
#pragma unroll
        for (int ct = 0; ct < 8; ++ct) {
            const int slotB = (ct * 16 + l16) * 4 + qx;
            bf16x8 b = *(const bf16x8*)&lds[cb][4096 + slotB * 8];
            acc[0][ct] = __builtin_amdgcn_mfma_f32_16x16x32_bf16(a0, b, acc[0][ct], 0, 0, 0);
            acc[1][ct] = __builtin_amdgcn_mfma_f32_16x16x32_bf16(a1, b, acc[1][ct], 0, 0, 0);
        }
    };

    const int nsteps = nTerms * 4;
    stage(0, 0);
    __syncthreads();
    for (int s = 0; s < nsteps; ++s) {
        const int cb = s & 1;
        if (s + 1 < nsteps) stage(s + 1, cb ^ 1);
        compute(cb);
        __syncthreads();
    }

    float bv[8];
#pragma unroll
    for (int ct = 0; ct < 8; ++ct) bv[ct] = bias[ct * 16 + l16];

    float psum[8], psq[8];
#pragma unroll
    for (int ct = 0; ct < 8; ++ct) { psum[ct] = 0.f; psq[ct] = 0.f; }

#pragma unroll
    for (int rt = 0; rt < 2; ++rt)
#pragma unroll
        for (int i = 0; i < 4; ++i) {
            int row = row0 + wave * 32 + rt * 16 + quad * 4 + i;
            if (row < N) {
#pragma unroll
                for (int ct = 0; ct < 8; ++ct) {
                    float v = acc[rt][ct][i] + bv[ct];
                    out[(size_t)row * D + ct * 16 + l16] = v;
                    psum[ct] += v;
                    psq[ct] += v * v;
                }
            }
        }

#pragma unroll
    for (int ct = 0; ct < 8; ++ct) {
        atomicAdd(&sstat[ct * 16 + l16], psum[ct]);
        atomicAdd(&sstat[128 + ct * 16 + l16], psq[ct]);
    }
    __syncthreads();
    if (tx < 128) {
        atomAddF(&gsum[tx], sstat[tx]);
        atomAddF(&gsq[tx], sstat[128 + tx]);
    }
}

// ---------------- fused normalize+relu with per-block stats finalization ----------------
__global__ void norm_relu_fin(float* __restrict__ buf,
                              long nvecVar, long nvecTot,
                              const float* __restrict__ stats,
                              const float* __restrict__ wv, const float* __restrict__ bv, const float* __restrict__ msv,
                              const float* __restrict__ wc, const float* __restrict__ bc, const float* __restrict__ msc,
                              int Nvar, int Ncon) {
    __shared__ float ss[512];   // [0:128) scale_var [128:256) shift_var [256:384) scale_con [384:512) shift_con
    const int t = threadIdx.x;
    {
        const int col = t & 127;
        const bool isv = t < 128;
        const float n = isv ? (float)Nvar : (float)Ncon;
        const float* st = stats + (isv ? 0 : 256);
        const float mu = st[col] / n;
        const float ex2 = st[128 + col] / n;
        const float ms = (isv ? msv : msc)[col];
        const float var = ex2 - 2.f * ms * mu * mu + ms * ms * mu * mu;
        const float istd = rsqrtf(var + 1e-5f);
        const float sc = (isv ? wv : wc)[col] * istd;
        ss[(isv ? 0 : 256) + col] = sc;
        ss[(isv ? 128 : 384) + col] = (isv ? bv : bc)[col] - sc * ms * mu;
    }
    __syncthreads();
    long i = (long)blockIdx.x * blockDim.x + t;
    if (i >= nvecTot) return;
    const int base = (i < nvecVar) ? 0 : 256;
    const int q = ((int)i & 31) * 4;
    float4 v = *(float4*)(buf + i * 4);
    float4 o;
    o.x = fmaxf(0.f, v.x * ss[base + q + 0] + ss[base + 128 + q + 0]);
    o.y = fmaxf(0.f, v.y * ss[base + q + 1] + ss[base + 128 + q + 1]);
    o.z = fmaxf(0.f, v.z * ss[base + q + 2] + ss[base + 128 + q + 2]);
    o.w = fmaxf(0.f, v.w * ss[base + q + 3] + ss[base + 128 + q + 3]);
    *(float4*)(buf + i * 4) = o;
}

extern "C" void kernel_launch(void* const* d_in, const int* in_sizes, int n_in,
                              void* d_out, int out_size, void* d_ws, size_t ws_size,
                              hipStream_t stream) {
    const float* x_var = (const float*)d_in[0];
    const float* x_con = (const float*)d_in[1];
    const float* x_reg = (const float*)d_in[2];
    const int* src_adj = (const int*)d_in[3];
    const int* dst_adj = (const int*)d_in[4];
    const int* src_t   = (const int*)d_in[5];
    const int* dst_t   = (const int*)d_in[6];
    const int* src_g   = (const int*)d_in[7];
    const int* dst_g   = (const int*)d_in[8];
    const float* W_rel_adj  = (const float*)d_in[9];
    const float* b_adj      = (const float*)d_in[10];
    const float* W_root_adj = (const float*)d_in[11];
    const float* W_rel_t    = (const float*)d_in[12];
    const float* b_t        = (const float*)d_in[13];
    const float* W_root_t   = (const float*)d_in[14];
    const float* W_rel_g    = (const float*)d_in[15];
    const float* b_g        = (const float*)d_in[16];
    const float* W_root_g   = (const float*)d_in[17];
    const float* gnw_v  = (const float*)d_in[18];
    const float* gnb_v  = (const float*)d_in[19];
    const float* gnms_v = (const float*)d_in[20];
    const float* gnw_c  = (const float*)d_in[21];
    const float* gnb_c  = (const float*)d_in[22];
    const float* gnms_c = (const float*)d_in[23];

    const int Nvar = in_sizes[0] / D;
    const int Ncon = in_sizes[1] / D;
    const int Nreg = in_sizes[2] / D;
    const int Eadj = in_sizes[3];
    const int Et   = in_sizes[5];
    const int Eg   = in_sizes[7];

    const int nbV = (Nvar + 255) >> 8;     // bins per var-dst graph (adj, groups)
    const int nbC = (Ncon + 255) >> 8;     // bins for touch
    const int totBins = 2 * nbV + nbC;

    // ---- workspace layout (large blocks first, all 256B-aligned) ----
    char* p = (char*)d_ws;
    unsigned short* xv_bf = (unsigned short*)p; p += (size_t)Nvar * D * 2;
    unsigned short* xc_bf = (unsigned short*)p; p += (size_t)Ncon * D * 2;
    unsigned short* xr_bf = (unsigned short*)p; p += (size_t)Nreg * D * 2;
    unsigned short* agg_adj = (unsigned short*)p; p += (size_t)Nvar * D * 2;
    unsigned short* agg_g   = (unsigned short*)p; p += (size_t)Nvar * D * 2;
    unsigned short* agg_t   = (unsigned short*)p; p += (size_t)Ncon * D * 2;
    unsigned int* pairs = (unsigned int*)p; p += (size_t)SEGS * totBins * CAP_SEG * 4;
    unsigned int* csr   = (unsigned int*)p; p += (size_t)totBins * CSRB * 4;
    int* segcnt = (int*)p; p += (size_t)SEGS * totBins * 4;
    unsigned int* rowinfo = (unsigned int*)p; p += (size_t)(2 * Nvar + Ncon) * 4;
    int* ovf0 = (int*)p; p += (size_t)Eadj * 4;
    int* ovf1 = (int*)p; p += (size_t)Eg * 4;
    int* ovf2 = (int*)p; p += (size_t)Et * 4;
    unsigned short* Wt_adj    = (unsigned short*)p; p += D * D * 2;
    unsigned short* Wt_g      = (unsigned short*)p; p += D * D * 2;
    unsigned short* Wt_t      = (unsigned short*)p; p += D * D * 2;
    unsigned short* Wt_root_t = (unsigned short*)p; p += D * D * 2;
    unsigned short* Wt_sum    = (unsigned short*)p; p += D * D * 2;
    float* bsum  = (float*)p; p += D * 4;
    // ---- contiguous zero region: stats(512f) + ovf_cnt(64i) ----
    char* zbase = p;
    float* stats   = (float*)p; p += 512 * 4;
    int* ovf_cnt   = (int*)p;   p += 64 * 4;         // [0],[16],[32] used
    const long zwords = (long)(p - zbase) / 4;

    float* out_var = (float*)d_out;
    float* out_con = out_var + (size_t)Nvar * D;

    // 1: fused weights-prep + zero + casts
    {
        long n4v = (long)Nvar * 32, n4c = (long)Ncon * 32, n4r = (long)Nreg * 32;
        long tot = (long)D * D + zwords + n4v + n4c + n4r;
        prep_cast_zero<<<(int)((tot + 255) / 256), 256, 0, stream>>>(
            W_rel_adj, W_rel_g, W_rel_t, W_root_t, W_root_adj, W_root_g, b_adj, b_g,
            Wt_adj, Wt_g, Wt_t, Wt_root_t, Wt_sum, bsum,
            (unsigned int*)zbase, zwords,
            x_var, n4v, x_con, n4c, x_reg, n4r, xv_bf, xc_bf, xr_bf);
    }

    // 2: single-pass private-segment binning, tile-interleaved (grid MUST be SEGS)
    binscatter3<<<SEGS, 256, 0, stream>>>(
        src_adj, dst_adj, Eadj,
        src_g,   dst_g,   Eg,
        src_t,   dst_t,   Et,
        nbV, totBins, pairs, segcnt, ovf0, ovf1, ovf2, ovf_cnt);

    // 3: per-bin CSR build (blockDim MUST be SEGS)
    build_csr<<<totBins, SEGS, 0, stream>>>(nbV, Nvar, Ncon, totBins, pairs, segcnt, csr, rowinfo);

    // 4: pull-aggregate from CSR (4 rows per wave)
    {
        long rows = (long)2 * Nvar + Ncon;
        long T = ((rows + 3) / 4) * 64;
        pull_csr3<<<(int)((T + 255) / 256), 256, 0, stream>>>(
            Nvar, Ncon, nbV, xv_bf, xr_bf,
            csr, rowinfo,
            src_adj, dst_adj, ovf0,
            src_g,   dst_g,   ovf1,
            src_t,   dst_t,   ovf2,
            ovf_cnt, agg_adj, agg_g, agg_t);
    }

    // 5,6: GEMMs — SPLIT dispatches (merge doubles HBM traffic; see gemm_fused comment)
    gemm_fused<<<(Nvar + 127) / 128, 256, 0, stream>>>(Nvar,
        agg_adj, Wt_adj, agg_g, Wt_g, xv_bf, Wt_sum, 3,
        bsum, out_var, stats, stats + 128);
    gemm_fused<<<(Ncon + 127) / 128, 256, 0, stream>>>(Ncon,
        agg_t, Wt_t, xc_bf, Wt_root_t, nullptr, nullptr, 2,
        b_t, out_con, stats + 256, stats + 384);

    // 7: fused normalize+relu+finalize over the contiguous [out_var | out_con] buffer
    {
        long nvecVar = (long)Nvar * 32;
        long nvecTot = (long)(Nvar + Ncon) * 32;
        norm_relu_fin<<<(int)((nvecTot + 255) / 256), 256, 0, stream>>>(
            out_var, nvecVar, nvecTot, stats,
            gnw_v, gnb_v, gnms_v, gnw_c, gnb_c, gnms_c, Nvar, Ncon);
    }
}

// Round 14
// 660.257 us; speedup vs baseline: 1.1150x; 1.0255x over previous
//
#include <hip/hip_runtime.h>
#include <hip/hip_bf16.h>

#define D 128
#define SEGS 256      // binscatter grid size == build_csr blockDim (segment <-> thread mapping)
#define TILE 1024     // edge tile (4 x 256); tiles round-robin across blocks -> per-(block,bin)
                      // load is graph-MIXED: worst lambda ~5 (R10 lesson: contiguous chunks gave
                      // graph-LOCAL lambda ~20 for touch -> mass segment overflow -> 9.7ms scan)
#define CAP_SEG 32    // P(Poisson(5) > 32) ~ 1e-9 per cell; ovf fallback exact
#define CSRB 8192     // CSR capacity per bin = SEGS*CAP_SEG -> bin overflow structurally impossible
#define MAXBINS 4096  // LDS bin-counter capacity (harness: ~1955 bins)

// pairs layout [seg][bin][slot] — R11-verbatim (best measured 671.6us; R13's [bin][seg][slot]
// transpose predicted +20-30us on build_csr and delivered 0 — reverted).

typedef __attribute__((ext_vector_type(8))) short bf16x8;
typedef __attribute__((ext_vector_type(4))) float f32x4;

__device__ __forceinline__ void atomAddF(float* p, float v) { unsafeAtomicAdd(p, v); }

__device__ __forceinline__ unsigned short f2bf(float f) {
    __hip_bfloat16 h = __float2bfloat16(f);
    return *reinterpret_cast<unsigned short*>(&h);
}
__device__ __forceinline__ float bf2f(unsigned int u16) {
    unsigned int x = u16 << 16;
    return *reinterpret_cast<float*>(&x);
}
// acc += ab.lo_bf16 * w.lo_bf16 + ab.hi_bf16 * w.hi_bf16   (one VALU op for 2 values)
__device__ __forceinline__ void dot2bf(float& acc, unsigned int ab, unsigned int w) {
    asm("v_dot2_f32_bf16 %0, %1, %2, %0" : "+v"(acc) : "v"(ab), "v"(w));
}
// dst = (bf16(lo), bf16(hi)) packed, RNE — 1 op vs 2 software-RNE sequences
__device__ __forceinline__ unsigned int pk_bf16(float lo, float hi) {
    unsigned int r;
    asm("v_cvt_pk_bf16_f32 %0, %1, %2" : "=v"(r) : "v"(lo), "v"(hi));
    return r;
}

// ---------------- fused: weights-prep + zero-region + cast fp32->bf16 (x3) ----------------
__global__ void prep_cast_zero(const float* __restrict__ Wra, const float* __restrict__ Wrg,
                               const float* __restrict__ Wrt, const float* __restrict__ Wroot_t,
                               const float* __restrict__ Wroot_a, const float* __restrict__ Wroot_g,
                               const float* __restrict__ ba, const float* __restrict__ bg,
                               unsigned short* __restrict__ Wt_adj, unsigned short* __restrict__ Wt_g,
                               unsigned short* __restrict__ Wt_t, unsigned short* __restrict__ Wt_root_t,
                               unsigned short* __restrict__ Wt_sum, float* __restrict__ bsum,
                               unsigned int* __restrict__ zbase, long zwords,
                               const float* __restrict__ xa, long n4a,
                               const float* __restrict__ xb, long n4b,
                               const float* __restrict__ xc, long n4c,
                               unsigned short* __restrict__ oa,
                               unsigned short* __restrict__ ob,
                               unsigned short* __restrict__ oc) {
    long gid = (long)blockIdx.x * blockDim.x + threadIdx.x;
    if (gid < D * D) {
        int i = (int)gid;
        int k = i >> 7, n = i & 127;
        int ti = n * D + k;
        Wt_adj[ti]    = f2bf(Wra[i]);
        Wt_g[ti]      = f2bf(Wrg[i]);
        Wt_t[ti]      = f2bf(Wrt[i]);
        Wt_root_t[ti] = f2bf(Wroot_t[i]);
        Wt_sum[ti]    = f2bf(Wroot_a[i] + Wroot_g[i]);
        if (i < D) bsum[i] = ba[i] + bg[i];
        return;
    }
    gid -= D * D;
    if (gid < zwords) { zbase[gid] = 0u; return; }
    gid -= zwords;
    const float* in; unsigned short* out; long li;
    if (gid < n4a)                 { in = xa; out = oa; li = gid; }
    else if (gid < n4a + n4b)      { in = xb; out = ob; li = gid - n4a; }
    else if (gid < n4a + n4b + n4c){ in = xc; out = oc; li = gid - n4a - n4b; }
    else return;
    float4 v = ((const float4*)in)[li];
    ushort4 o;
    o.x = f2bf(v.x); o.y = f2bf(v.y); o.z = f2bf(v.z); o.w = f2bf(v.w);
    ((ushort4*)out)[li] = o;
}

// ---------------- pass 1: single-pass private-segment binning, tile-interleaved ----------------
__launch_bounds__(256)
__global__ void binscatter3(const int* __restrict__ s0, const int* __restrict__ d0, int E0,
                            const int* __restrict__ s1, const int* __restrict__ d1, int E1,
                            const int* __restrict__ s2, const int* __restrict__ d2, int E2,
                            int nbV, int totBins,
                            unsigned int* __restrict__ pairs, int* __restrict__ segcnt,
                            int* __restrict__ o0, int* __restrict__ o1, int* __restrict__ o2,
                            int* __restrict__ ovf_cnt) {
    __shared__ int lb[MAXBINS];
    const int t = threadIdx.x;
    const long Etot = (long)E0 + E1 + E2;
    const long nTiles = (Etot + TILE - 1) / TILE;

    for (int b = t; b < totBins; b += 256) lb[b] = 0;
    __syncthreads();

    const long segBase = (long)blockIdx.x * totBins;
    for (long tile = blockIdx.x; tile < nTiles; tile += SEGS) {
        const long tbase = tile * TILE;
#pragma unroll
        for (int u = 0; u < 4; ++u) {               // 4 independent edge loads in flight
            long e = tbase + (long)u * 256 + t;
            if (e >= Etot) break;
            int s, d, le, bidx, g;
            if (e < E0)                 { le = (int)e;             s = s0[le]; d = d0[le]; bidx = (d >> 8);           g = 0; }
            else if (e < (long)E0 + E1) { le = (int)(e - E0);      s = s1[le]; d = d1[le]; bidx = nbV + (d >> 8);     g = 1; }
            else                        { le = (int)(e - E0 - E1); s = s2[le]; d = d2[le]; bidx = 2 * nbV + (d >> 8); g = 2; }
            int slot = atomicAdd(&lb[bidx], 1);     // LDS cursor
            if (slot < CAP_SEG)
                pairs[(segBase + bidx) * CAP_SEG + slot] = ((unsigned int)s << 8) | (unsigned int)(d & 255);
            else {
                int* ovf = (g == 0) ? o0 : ((g == 1) ? o1 : o2);
                ovf[atomicAdd(&ovf_cnt[g * 16], 1)] = le;   // exact fallback, ~never
            }
        }
    }
    __syncthreads();
    for (int b = t; b < totBins; b += 256) {
        int c = lb[b];
        segcnt[segBase + b] = (c > CAP_SEG) ? CAP_SEG : c;
    }
}

// ---------------- pass 2: per-bin CSR build from 256 segments (thread t <-> segment t) ----------------
__launch_bounds__(256)
__global__ void build_csr(int nbV, int Nvar, int Ncon, int totBins,
                          const unsigned int* __restrict__ pairs, const int* __restrict__ segcnt,
                          unsigned int* __restrict__ csr, unsigned int* __restrict__ rowinfo) {
    const int b = blockIdx.x;
    int N, dstBase, infoBase;
    if (b < nbV)          { N = Nvar; dstBase = b * 256;             infoBase = 0; }
    else if (b < 2 * nbV) { N = Nvar; dstBase = (b - nbV) * 256;     infoBase = Nvar; }
    else                  { N = Ncon; dstBase = (b - 2 * nbV) * 256; infoBase = 2 * Nvar; }

    __shared__ int hist[256], scan[256], cur[256];
    const int t = threadIdx.x;
    const long segBase = ((long)t * totBins + b) * CAP_SEG;   // thread t's segment of this bin
    const int sc = segcnt[(long)t * totBins + b];

    hist[t] = 0;
    __syncthreads();
    for (int i = 0; i < sc; ++i) atomicAdd(&hist[pairs[segBase + i] & 255], 1);
    __syncthreads();
    scan[t] = hist[t];
    __syncthreads();
    for (int off = 1; off < 256; off <<= 1) {
        int u = (t >= off) ? scan[t - off] : 0;
        __syncthreads();
        scan[t] += u;
        __syncthreads();
    }
    const int excl = scan[t] - hist[t];
    cur[t] = excl;
    if (dstBase + t < N)
        rowinfo[infoBase + dstBase + t] = ((unsigned int)excl << 16) | (unsigned int)hist[t];
    __syncthreads();
    for (int i = 0; i < sc; ++i) {
        unsigned int pr = pairs[segBase + i];
        int slot = atomicAdd(&cur[pr & 255], 1);   // LDS atomic
        csr[(long)b * CSRB + slot] = pr >> 8;      // src index; slot < SEGS*CAP_SEG = CSRB always
    }
}

// ---------------- pass 3: pull-aggregate from CSR — 4 dst rows per wave ----------------
__launch_bounds__(256)
__global__ void pull_csr3(int Nvar, int Ncon, int nbV,
                          const unsigned short* __restrict__ xv, const unsigned short* __restrict__ xr,
                          const unsigned int* __restrict__ csr, const unsigned int* __restrict__ rowinfo,
                          const int* __restrict__ s0, const int* __restrict__ d0, const int* __restrict__ o0,
                          const int* __restrict__ s1, const int* __restrict__ d1, const int* __restrict__ o1,
                          const int* __restrict__ s2, const int* __restrict__ d2, const int* __restrict__ o2,
                          const int* __restrict__ ovf_cnt,
                          unsigned short* __restrict__ agg_adj, unsigned short* __restrict__ agg_g,
                          unsigned short* __restrict__ agg_t) {
    const int tx = threadIdx.x;
    const int lane = tx & 63;
    const int ql = lane & 15;            // column group: cols [ql*8 .. ql*8+7]
    const int sl = lane & 48;            // quarter base lane (q*16)
    const long colOff = (long)ql * 8;

    const long tot = 2L * Nvar + Ncon;
    const long wv = ((long)blockIdx.x * blockDim.x + tx) >> 6;
    long r = wv * 4 + (lane >> 4);       // this quarter's dst row (global id)
    const bool active = r < tot;
    if (!active) r = tot - 1;            // clamp for safe addressing; store guarded

    // per-lane graph selection (uniform within quarter)
    const bool g1 = (r >= Nvar) && (r < 2L * Nvar);
    const bool g2 = (r >= 2L * Nvar);
    const unsigned short* y = g1 ? xr : xv;
    const int wid = (int)(r - (g1 ? (long)Nvar : 0) - (g2 ? 2L * Nvar : 0));
    const int infoBase = g1 ? Nvar : (g2 ? 2 * Nvar : 0);
    const long binBase = g1 ? nbV : (g2 ? 2L * nbV : 0);
    unsigned short* agg = g1 ? agg_g : (g2 ? agg_t : agg_adj);

    const unsigned int info = rowinfo[infoBase + wid];
    const int mc = active ? (int)(info & 0xffffu) : 0;
    const long b = binBase + (wid >> 8);
    const long cbase = b * CSRB + (long)(info >> 16);

    float a0 = 0.f, a1 = 0.f, a2 = 0.f, a3 = 0.f, a4 = 0.f, a5 = 0.f, a6 = 0.f, a7 = 0.f;

    for (int base = 0; __any(base < mc); base += 16) {
        int idx = (base + ql < mc) ? (int)csr[cbase + base + ql] : 0;
        for (int jj = 0; jj < 16; jj += 4) {
            const int e = base + jj;
            if (!__any(e < mc)) break;
            int i0 = __shfl(idx, sl + jj + 0, 64);   // edge e of OWN quarter's row
            int i1 = __shfl(idx, sl + jj + 1, 64);
            int i2 = __shfl(idx, sl + jj + 2, 64);
            int i3 = __shfl(idx, sl + jj + 3, 64);
            uint4 r0 = *(const uint4*)(y + (long)i0 * D + colOff);
            uint4 r1 = *(const uint4*)(y + (long)i1 * D + colOff);
            uint4 r2 = *(const uint4*)(y + (long)i2 * D + colOff);
            uint4 r3 = *(const uint4*)(y + (long)i3 * D + colOff);
            unsigned int w01 = ((e     < mc) ? 0x3F80u : 0u) | ((e + 1 < mc) ? 0x3F800000u : 0u);
            unsigned int w23 = ((e + 2 < mc) ? 0x3F80u : 0u) | ((e + 3 < mc) ? 0x3F800000u : 0u);
            unsigned int p;
            // perm 0x01000504: (src0.lo_bf16, src1.lo_bf16); 0x03020706: high halves
            p = __builtin_amdgcn_perm(r0.x, r1.x, 0x01000504u); dot2bf(a0, p, w01);
            p = __builtin_amdgcn_perm(r2.x, r3.x, 0x01000504u); dot2bf(a0, p, w23);
            p = __builtin_amdgcn_perm(r0.x, r1.x, 0x03020706u); dot2bf(a1, p, w01);
            p = __builtin_amdgcn_perm(r2.x, r3.x, 0x03020706u); dot2bf(a1, p, w23);
            p = __builtin_amdgcn_perm(r0.y, r1.y, 0x01000504u); dot2bf(a2, p, w01);
            p = __builtin_amdgcn_perm(r2.y, r3.y, 0x01000504u); dot2bf(a2, p, w23);
            p = __builtin_amdgcn_perm(r0.y, r1.y, 0x03020706u); dot2bf(a3, p, w01);
            p = __builtin_amdgcn_perm(r2.y, r3.y, 0x03020706u); dot2bf(a3, p, w23);
            p = __builtin_amdgcn_perm(r0.z, r1.z, 0x01000504u); dot2bf(a4, p, w01);
            p = __builtin_amdgcn_perm(r2.z, r3.z, 0x01000504u); dot2bf(a4, p, w23);
            p = __builtin_amdgcn_perm(r0.z, r1.z, 0x03020706u); dot2bf(a5, p, w01);
            p = __builtin_amdgcn_perm(r2.z, r3.z, 0x03020706u); dot2bf(a5, p, w23);
            p = __builtin_amdgcn_perm(r0.w, r1.w, 0x01000504u); dot2bf(a6, p, w01);
            p = __builtin_amdgcn_perm(r2.w, r3.w, 0x01000504u); dot2bf(a6, p, w23);
            p = __builtin_amdgcn_perm(r0.w, r1.w, 0x03020706u); dot2bf(a7, p, w01);
            p = __builtin_amdgcn_perm(r2.w, r3.w, 0x03020706u); dot2bf(a7, p, w23);
        }
    }

    // rare exact fallback: only if some edge of this graph overflowed its segment
    const int oc = ovf_cnt[g1 ? 16 : (g2 ? 32 : 0)];
    if (active && oc > 0) {
        const int* srcp = g1 ? s1 : (g2 ? s2 : s0);
        const int* dstp = g1 ? d1 : (g2 ? d2 : d0);
        const int* ovf  = g1 ? o1 : (g2 ? o2 : o0);
        for (int i = 0; i < oc; ++i) {
            int e = ovf[i];
            if (dstp[e] == wid) {        // every lane of the quarter adds its own cols
                int s = srcp[e];
                uint4 rr = *(const uint4*)(y + (long)s * D + colOff);
                a0 += bf2f(rr.x & 0xffffu); a1 += bf2f(rr.x >> 16);
                a2 += bf2f(rr.y & 0xffffu); a3 += bf2f(rr.y >> 16);
                a4 += bf2f(rr.z & 0xffffu); a5 += bf2f(rr.z >> 16);
                a6 += bf2f(rr.w & 0xffffu); a7 += bf2f(rr.w >> 16);
            }
        }
    }

    if (active) {
        uint4 o;
        o.x = pk_bf16(a0, a1);
        o.y = pk_bf16(a2, a3);
        o.z = pk_bf16(a4, a5);
        o.w = pk_bf16(a6, a7);
        *(uint4*)(agg + (long)wid * D + colOff) = o;
    }
}

// ---------------- fused MFMA GEMM, LDS-staged (m97-style 2-phase) ----------------
// SPLIT var/con dispatches REQUIRED: merging (R4, R12) doubles HBM traffic (+66us).
// R14 changes (epilogue/occupancy only; K-loop untouched):
//  - sstat ALIASES lds[0] (dead after final barrier) -> LDS block 33792->32768 B
//    -> 5 blocks/CU (160/32) instead of 4; launch_bounds(256,5) caps VGPR accordingly.
//  - quad-reduce (shfl_xor 16/32) before sstat atomics -> 1 lane/address/wave
//    (kills the 3.0M SQ_LDS_BANK_CONFLICT cycles from 4-way atomic aliasing).
__launch_bounds__(256, 5)
__global__ void gemm_fused(int N,
                           const unsigned short* __restrict__ A0, const unsigned short* __restrict__ Wt0,
                           const unsigned short* __restrict__ A1, const unsigned short* __restrict__ Wt1,
                           const unsigned short* __restrict__ A2, const unsigned short* __restrict__ Wt2,
                           int nTerms,
                           const float* __restrict__ bias, float* __restrict__ out,
                           float* __restrict__ gsum, float* __restrict__ gsq) {
    __shared__ unsigned short lds[2][8192];   // per buf: A slots 0..511 (8KB), B slots at +4096 (8KB)
    const int tx = threadIdx.x;

    const int wave = tx >> 6, lane = tx & 63;
    const int quad = lane >> 4, l16 = lane & 15;
    const int row0 = blockIdx.x * 128;

    const int sA0 = tx, sA1 = tx + 256;
    const int rS0 = sA0 >> 2, qS0 = (sA0 & 3) ^ ((sA0 >> 4) & 3);
    const int rS1 = sA1 >> 2, qS1 = (sA1 & 3) ^ ((sA1 >> 4) & 3);
    long gr0 = (long)row0 + rS0; if (gr0 >= N) gr0 = N - 1;
    long gr1 = (long)row0 + rS1; if (gr1 >= N) gr1 = N - 1;

    f32x4 acc[2][8];
#pragma unroll
    for (int rt = 0; rt < 2; ++rt)
#pragma unroll
        for (int ct = 0; ct < 8; ++ct)
#pragma unroll
            for (int i = 0; i < 4; ++i) acc[rt][ct][i] = 0.f;

    auto stage = [&](int s, int bb) {
        const int t = s >> 2;
        const int k0 = (s & 3) * 32;
        const unsigned short* A = (t == 0) ? A0 : ((t == 1) ? A1 : A2);
        const unsigned short* W = (t == 0) ? Wt0 : ((t == 1) ? Wt1 : Wt2);
        __builtin_amdgcn_global_load_lds(
            (const __attribute__((address_space(1))) unsigned int*)(A + gr0 * D + k0 + qS0 * 8),
            (__attribute__((address_space(3))) unsigned int*)(&lds[bb][sA0 * 8]), 16, 0, 0);
        __builtin_amdgcn_global_load_lds(
            (const __attribute__((address_space(1))) unsigned int*)(A + gr1 * D + k0 + qS1 * 8),
            (__attribute__((address_space(3))) unsigned int*)(&lds[bb][sA1 * 8]), 16, 0, 0);
        __builtin_amdgcn_global_load_lds(
            (const __attribute__((address_space(1))) unsigned int*)(W + (long)rS0 * D + k0 + qS0 * 8),
            (__attribute__((address_space(3))) unsigned int*)(&lds[bb][4096 + sA0 * 8]), 16, 0, 0);
        __builtin_amdgcn_global_load_lds(
            (const __attribute__((address_space(1))) unsigned int*)(W + (long)rS1 * D + k0 + qS1 * 8),
            (__attribute__((address_space(3))) unsigned int*)(&lds[bb][4096 + sA1 * 8]), 16, 0, 0);
    };

    const int xq = (l16 >> 2) & 3;
    const int qx = quad ^ xq;

    auto compute = [&](int cb) {
        const int slotA0 = (wave * 32 + l16) * 4 + qx;
        const int slotA1 = (wave * 32 + 16 + l16) * 4 + qx;
        bf16x8 a0 = *(const bf16x8*)&lds[cb][slotA0 * 8];
        bf16x8 a1 = *(const bf16x8*)&lds[cb][slotA1 * 8];
#pragma unroll
        for (int ct = 0; ct < 8; ++ct) {
            const int slotB = (ct * 16 + l16) * 4 + qx;
            bf16x8 b = *(const bf16x8*)&lds[cb][4096 + slotB * 8];
            acc[0][ct] = __builtin_amdgcn_mfma_f32_16x16x32_bf16(a0, b, acc[0][ct], 0, 0, 0);
            acc[1][ct] = __builtin_amdgcn_mfma_f32_16x16x32_bf16(a1, b, acc[1][ct], 0, 0, 0);
        }
    };

    const int nsteps = nTerms * 4;
    stage(0, 0);
    __syncthreads();
    for (int s = 0; s < nsteps; ++s) {
        const int cb = s & 1;
        if (s + 1 < nsteps) stage(s + 1, cb ^ 1);
        compute(cb);
        __syncthreads();                  // last iteration: all waves done reading LDS -> safe to alias
    }

    // epilogue: bias, store, per-column partial stats
    float bv[8];
#pragma unroll
    for (int ct = 0; ct < 8; ++ct) bv[ct] = bias[ct * 16 + l16];

    float psum[8], psq[8];
#pragma unroll
    for (int ct = 0; ct < 8; ++ct) { psum[ct] = 0.f; psq[ct] = 0.f; }

#pragma unroll
    for (int rt = 0; rt < 2; ++rt)
#pragma unroll
        for (int i = 0; i < 4; ++i) {
            int row = row0 + wave * 32 + rt * 16 + quad * 4 + i;
            if (row < N) {
#pragma unroll
                for (int ct = 0; ct < 8; ++ct) {
                    float v = acc[rt][ct][i] + bv[ct];
                    out[(size_t)row * D + ct * 16 + l16] = v;
                    psum[ct] += v;
                    psq[ct] += v * v;
                }
            }
        }

    // quad-reduce: lanes {l16, l16+16, l16+32, l16+48} hold the same column ct*16+l16
#pragma unroll
    for (int ct = 0; ct < 8; ++ct) {
        psum[ct] += __shfl_xor(psum[ct], 16, 64);
        psum[ct] += __shfl_xor(psum[ct], 32, 64);
        psq[ct]  += __shfl_xor(psq[ct], 16, 64);
        psq[ct]  += __shfl_xor(psq[ct], 32, 64);
    }

    // block stats staging reuses lds (K-loop data dead)
    float* sstat = (float*)&lds[0][0];
    sstat[tx] = 0.f;
    __syncthreads();
    if (quad == 0) {
#pragma unroll
        for (int ct = 0; ct < 8; ++ct) {
            atomicAdd(&sstat[ct * 16 + l16], psum[ct]);
            atomicAdd(&sstat[128 + ct * 16 + l16], psq[ct]);
        }
    }
    __syncthreads();
    if (tx < 128) {
        atomAddF(&gsum[tx], sstat[tx]);
        atomAddF(&gsq[tx], sstat[128 + tx]);
    }
}

// ---------------- fused normalize+relu with per-block stats finalization ----------------
__global__ void norm_relu_fin(float* __restrict__ buf,
                              long nvecVar, long nvecTot,
                              const float* __restrict__ stats,
                              const float* __restrict__ wv, const float* __restrict__ bv, const float* __restrict__ msv,
                              const float* __restrict__ wc, const float* __restrict__ bc, const float* __restrict__ msc,
                              int Nvar, int Ncon) {
    __shared__ float ss[512];   // [0:128) scale_var [128:256) shift_var [256:384) scale_con [384:512) shift_con
    const int t = threadIdx.x;
    {
        const int col = t & 127;
        const bool isv = t < 128;
        const float n = isv ? (float)Nvar : (float)Ncon;
        const float* st = stats + (isv ? 0 : 256);
        const float mu = st[col] / n;
        const float ex2 = st[128 + col] / n;
        const float ms = (isv ? msv : msc)[col];
        const float var = ex2 - 2.f * ms * mu * mu + ms * ms * mu * mu;
        const float istd = rsqrtf(var + 1e-5f);
        const float sc = (isv ? wv : wc)[col] * istd;
        ss[(isv ? 0 : 256) + col] = sc;
        ss[(isv ? 128 : 384) + col] = (isv ? bv : bc)[col] - sc * ms * mu;
    }
    __syncthreads();
    long i = (long)blockIdx.x * blockDim.x + t;
    if (i >= nvecTot) return;
    const int base = (i < nvecVar) ? 0 : 256;
    const int q = ((int)i & 31) * 4;
    float4 v = *(float4*)(buf + i * 4);
    float4 o;
    o.x = fmaxf(0.f, v.x * ss[base + q + 0] + ss[base + 128 + q + 0]);
    o.y = fmaxf(0.f, v.y * ss[base + q + 1] + ss[base + 128 + q + 1]);
    o.z = fmaxf(0.f, v.z * ss[base + q + 2] + ss[base + 128 + q + 2]);
    o.w = fmaxf(0.f, v.w * ss[base + q + 3] + ss[base + 128 + q + 3]);
    *(float4*)(buf + i * 4) = o;
}

extern "C" void kernel_launch(void* const* d_in, const int* in_sizes, int n_in,
                              void* d_out, int out_size, void* d_ws, size_t ws_size,
                              hipStream_t stream) {
    const float* x_var = (const float*)d_in[0];
    const float* x_con = (const float*)d_in[1];
    const float* x_reg = (const float*)d_in[2];
    const int* src_adj = (const int*)d_in[3];
    const int* dst_adj = (const int*)d_in[4];
    const int* src_t   = (const int*)d_in[5];
    const int* dst_t   = (const int*)d_in[6];
    const int* src_g   = (const int*)d_in[7];
    const int* dst_g   = (const int*)d_in[8];
    const float* W_rel_adj  = (const float*)d_in[9];
    const float* b_adj      = (const float*)d_in[10];
    const float* W_root_adj = (const float*)d_in[11];
    const float* W_rel_t    = (const float*)d_in[12];
    const float* b_t        = (const float*)d_in[13];
    const float* W_root_t   = (const float*)d_in[14];
    const float* W_rel_g    = (const float*)d_in[15];
    const float* b_g        = (const float*)d_in[16];
    const float* W_root_g   = (const float*)d_in[17];
    const float* gnw_v  = (const float*)d_in[18];
    const float* gnb_v  = (const float*)d_in[19];
    const float* gnms_v = (const float*)d_in[20];
    const float* gnw_c  = (const float*)d_in[21];
    const float* gnb_c  = (const float*)d_in[22];
    const float* gnms_c = (const float*)d_in[23];

    const int Nvar = in_sizes[0] / D;
    const int Ncon = in_sizes[1] / D;
    const int Nreg = in_sizes[2] / D;
    const int Eadj = in_sizes[3];
    const int Et   = in_sizes[5];
    const int Eg   = in_sizes[7];

    const int nbV = (Nvar + 255) >> 8;     // bins per var-dst graph (adj, groups)
    const int nbC = (Ncon + 255) >> 8;     // bins for touch
    const int totBins = 2 * nbV + nbC;

    // ---- workspace layout (large blocks first, all 256B-aligned) ----
    char* p = (char*)d_ws;
    unsigned short* xv_bf = (unsigned short*)p; p += (size_t)Nvar * D * 2;
    unsigned short* xc_bf = (unsigned short*)p; p += (size_t)Ncon * D * 2;
    unsigned short* xr_bf = (unsigned short*)p; p += (size_t)Nreg * D * 2;
    unsigned short* agg_adj = (unsigned short*)p; p += (size_t)Nvar * D * 2;
    unsigned short* agg_g   = (unsigned short*)p; p += (size_t)Nvar * D * 2;
    unsigned short* agg_t   = (unsigned short*)p; p += (size_t)Ncon * D * 2;
    unsigned int* pairs = (unsigned int*)p; p += (size_t)SEGS * totBins * CAP_SEG * 4;
    unsigned int* csr   = (unsigned int*)p; p += (size_t)totBins * CSRB * 4;
    int* segcnt = (int*)p; p += (size_t)SEGS * totBins * 4;
    unsigned int* rowinfo = (unsigned int*)p; p += (size_t)(2 * Nvar + Ncon) * 4;
    int* ovf0 = (int*)p; p += (size_t)Eadj * 4;
    int* ovf1 = (int*)p; p += (size_t)Eg * 4;
    int* ovf2 = (int*)p; p += (size_t)Et * 4;
    unsigned short* Wt_adj    = (unsigned short*)p; p += D * D * 2;
    unsigned short* Wt_g      = (unsigned short*)p; p += D * D * 2;
    unsigned short* Wt_t      = (unsigned short*)p; p += D * D * 2;
    unsigned short* Wt_root_t = (unsigned short*)p; p += D * D * 2;
    unsigned short* Wt_sum    = (unsigned short*)p; p += D * D * 2;
    float* bsum  = (float*)p; p += D * 4;
    // ---- contiguous zero region: stats(512f) + ovf_cnt(64i) ----
    char* zbase = p;
    float* stats   = (float*)p; p += 512 * 4;
    int* ovf_cnt   = (int*)p;   p += 64 * 4;         // [0],[16],[32] used
    const long zwords = (long)(p - zbase) / 4;

    float* out_var = (float*)d_out;
    float* out_con = out_var + (size_t)Nvar * D;

    // 1: fused weights-prep + zero + casts
    {
        long n4v = (long)Nvar * 32, n4c = (long)Ncon * 32, n4r = (long)Nreg * 32;
        long tot = (long)D * D + zwords + n4v + n4c + n4r;
        prep_cast_zero<<<(int)((tot + 255) / 256), 256, 0, stream>>>(
            W_rel_adj, W_rel_g, W_rel_t, W_root_t, W_root_adj, W_root_g, b_adj, b_g,
            Wt_adj, Wt_g, Wt_t, Wt_root_t, Wt_sum, bsum,
            (unsigned int*)zbase, zwords,
            x_var, n4v, x_con, n4c, x_reg, n4r, xv_bf, xc_bf, xr_bf);
    }

    // 2: single-pass private-segment binning, tile-interleaved (grid MUST be SEGS)
    binscatter3<<<SEGS, 256, 0, stream>>>(
        src_adj, dst_adj, Eadj,
        src_g,   dst_g,   Eg,
        src_t,   dst_t,   Et,
        nbV, totBins, pairs, segcnt, ovf0, ovf1, ovf2, ovf_cnt);

    // 3: per-bin CSR build (blockDim MUST be SEGS)
    build_csr<<<totBins, SEGS, 0, stream>>>(nbV, Nvar, Ncon, totBins, pairs, segcnt, csr, rowinfo);

    // 4: pull-aggregate from CSR (4 rows per wave)
    {
        long rows = (long)2 * Nvar + Ncon;
        long T = ((rows + 3) / 4) * 64;
        pull_csr3<<<(int)((T + 255) / 256), 256, 0, stream>>>(
            Nvar, Ncon, nbV, xv_bf, xr_bf,
            csr, rowinfo,
            src_adj, dst_adj, ovf0,
            src_g,   dst_g,   ovf1,
            src_t,   dst_t,   ovf2,
            ovf_cnt, agg_adj, agg_g, agg_t);
    }

    // 5,6: GEMMs — SPLIT dispatches (merge doubles HBM traffic; see gemm_fused comment)
    gemm_fused<<<(Nvar + 127) / 128, 256, 0, stream>>>(Nvar,
        agg_adj, Wt_adj, agg_g, Wt_g, xv_bf, Wt_sum, 3,
        bsum, out_var, stats, stats + 128);
    gemm_fused<<<(Ncon + 127) / 128, 256, 0, stream>>>(Ncon,
        agg_t, Wt_t, xc_bf, Wt_root_t, nullptr, nullptr, 2,
        b_t, out_con, stats + 256, stats + 384);

    // 7: fused normalize+relu+finalize over the contiguous [out_var | out_con] buffer
    {
        long nvecVar = (long)Nvar * 32;
        long nvecTot = (long)(Nvar + Ncon) * 32;
        norm_relu_fin<<<(int)((nvecTot + 255) / 256), 256, 0, stream>>>(
            out_var, nvecVar, nvecTot, stats,
            gnw_v, gnb_v, gnms_v, gnw_c, gnb_c, gnms_c, Nvar, Ncon);
    }
}

// Round 16
// 658.771 us; speedup vs baseline: 1.1176x; 1.0023x over previous
//
#include <hip/hip_runtime.h>
#include <hip/hip_bf16.h>

#define D 128
#define SEGS 256      // binscatter grid size == build_csr blockDim (segment <-> thread mapping)
#define TILE 1024     // edge tile (4 x 256); tiles round-robin across blocks -> per-(block,bin)
                      // load is graph-MIXED: worst lambda ~5 (R10 lesson: contiguous chunks gave
                      // graph-LOCAL lambda ~20 for touch -> mass segment overflow -> 9.7ms scan)
#define CAP_SEG 32    // P(Poisson(5) > 32) ~ 1e-9 per cell; ovf fallback exact
#define CSRB 8192     // CSR capacity per bin = SEGS*CAP_SEG -> bin overflow structurally impossible
#define MAXBINS 4096  // LDS bin-counter capacity (harness: ~1955 bins)

// pairs layout [seg][bin][slot] — R11-verbatim (best measured; R13 transpose was null).
// GEMM K-loop uses __syncthreads() ONLY: raw s_barrier + counted vmcnt (R15) races —
// s_barrier doesn't drain lgkmcnt, and the compiler may sink MFMA+lgkmcnt waits past
// inline-asm barriers (rule #18), letting in-flight ds_reads race next-step LDS-DMA.

typedef __attribute__((ext_vector_type(8))) short bf16x8;
typedef __attribute__((ext_vector_type(4))) float f32x4;

__device__ __forceinline__ void atomAddF(float* p, float v) { unsafeAtomicAdd(p, v); }

__device__ __forceinline__ unsigned short f2bf(float f) {
    __hip_bfloat16 h = __float2bfloat16(f);
    return *reinterpret_cast<unsigned short*>(&h);
}
__device__ __forceinline__ float bf2f(unsigned int u16) {
    unsigned int x = u16 << 16;
    return *reinterpret_cast<float*>(&x);
}
// acc += ab.lo_bf16 * w.lo_bf16 + ab.hi_bf16 * w.hi_bf16   (one VALU op for 2 values)
__device__ __forceinline__ void dot2bf(float& acc, unsigned int ab, unsigned int w) {
    asm("v_dot2_f32_bf16 %0, %1, %2, %0" : "+v"(acc) : "v"(ab), "v"(w));
}
// dst = (bf16(lo), bf16(hi)) packed, RNE — 1 op vs 2 software-RNE sequences
__device__ __forceinline__ unsigned int pk_bf16(float lo, float hi) {
    unsigned int r;
    asm("v_cvt_pk_bf16_f32 %0, %1, %2" : "=v"(r) : "v"(lo), "v"(hi));
    return r;
}

// ---------------- fused: weights-prep + zero-region + cast fp32->bf16 (x3) ----------------
__global__ void prep_cast_zero(const float* __restrict__ Wra, const float* __restrict__ Wrg,
                               const float* __restrict__ Wrt, const float* __restrict__ Wroot_t,
                               const float* __restrict__ Wroot_a, const float* __restrict__ Wroot_g,
                               const float* __restrict__ ba, const float* __restrict__ bg,
                               unsigned short* __restrict__ Wt_adj, unsigned short* __restrict__ Wt_g,
                               unsigned short* __restrict__ Wt_t, unsigned short* __restrict__ Wt_root_t,
                               unsigned short* __restrict__ Wt_sum, float* __restrict__ bsum,
                               unsigned int* __restrict__ zbase, long zwords,
                               const float* __restrict__ xa, long n4a,
                               const float* __restrict__ xb, long n4b,
                               const float* __restrict__ xc, long n4c,
                               unsigned short* __restrict__ oa,
                               unsigned short* __restrict__ ob,
                               unsigned short* __restrict__ oc) {
    long gid = (long)blockIdx.x * blockDim.x + threadIdx.x;
    if (gid < D * D) {
        int i = (int)gid;
        int k = i >> 7, n = i & 127;
        int ti = n * D + k;
        Wt_adj[ti]    = f2bf(Wra[i]);
        Wt_g[ti]      = f2bf(Wrg[i]);
        Wt_t[ti]      = f2bf(Wrt[i]);
        Wt_root_t[ti] = f2bf(Wroot_t[i]);
        Wt_sum[ti]    = f2bf(Wroot_a[i] + Wroot_g[i]);
        if (i < D) bsum[i] = ba[i] + bg[i];
        return;
    }
    gid -= D * D;
    if (gid < zwords) { zbase[gid] = 0u; return; }
    gid -= zwords;
    const float* in; unsigned short* out; long li;
    if (gid < n4a)                 { in = xa; out = oa; li = gid; }
    else if (gid < n4a + n4b)      { in = xb; out = ob; li = gid - n4a; }
    else if (gid < n4a + n4b + n4c){ in = xc; out = oc; li = gid - n4a - n4b; }
    else return;
    float4 v = ((const float4*)in)[li];
    ushort4 o;
    o.x = f2bf(v.x); o.y = f2bf(v.y); o.z = f2bf(v.z); o.w = f2bf(v.w);
    ((ushort4*)out)[li] = o;
}

// ---------------- pass 1: single-pass private-segment binning, tile-interleaved ----------------
__launch_bounds__(256)
__global__ void binscatter3(const int* __restrict__ s0, const int* __restrict__ d0, int E0,
                            const int* __restrict__ s1, const int* __restrict__ d1, int E1,
                            const int* __restrict__ s2, const int* __restrict__ d2, int E2,
                            int nbV, int totBins,
                            unsigned int* __restrict__ pairs, int* __restrict__ segcnt,
                            int* __restrict__ o0, int* __restrict__ o1, int* __restrict__ o2,
                            int* __restrict__ ovf_cnt) {
    __shared__ int lb[MAXBINS];
    const int t = threadIdx.x;
    const long Etot = (long)E0 + E1 + E2;
    const long nTiles = (Etot + TILE - 1) / TILE;

    for (int b = t; b < totBins; b += 256) lb[b] = 0;
    __syncthreads();

    const long segBase = (long)blockIdx.x * totBins;
    for (long tile = blockIdx.x; tile < nTiles; tile += SEGS) {
        const long tbase = tile * TILE;
#pragma unroll
        for (int u = 0; u < 4; ++u) {               // 4 independent edge loads in flight
            long e = tbase + (long)u * 256 + t;
            if (e >= Etot) break;
            int s, d, le, bidx, g;
            if (e < E0)                 { le = (int)e;             s = s0[le]; d = d0[le]; bidx = (d >> 8);           g = 0; }
            else if (e < (long)E0 + E1) { le = (int)(e - E0);      s = s1[le]; d = d1[le]; bidx = nbV + (d >> 8);     g = 1; }
            else                        { le = (int)(e - E0 - E1); s = s2[le]; d = d2[le]; bidx = 2 * nbV + (d >> 8); g = 2; }
            int slot = atomicAdd(&lb[bidx], 1);     // LDS cursor
            if (slot < CAP_SEG)
                pairs[(segBase + bidx) * CAP_SEG + slot] = ((unsigned int)s << 8) | (unsigned int)(d & 255);
            else {
                int* ovf = (g == 0) ? o0 : ((g == 1) ? o1 : o2);
                ovf[atomicAdd(&ovf_cnt[g * 16], 1)] = le;   // exact fallback, ~never
            }
        }
    }
    __syncthreads();
    for (int b = t; b < totBins; b += 256) {
        int c = lb[b];
        segcnt[segBase + b] = (c > CAP_SEG) ? CAP_SEG : c;
    }
}

// ---------------- pass 2: per-bin CSR build from 256 segments (thread t <-> segment t) ----------------
__launch_bounds__(256)
__global__ void build_csr(int nbV, int Nvar, int Ncon, int totBins,
                          const unsigned int* __restrict__ pairs, const int* __restrict__ segcnt,
                          unsigned int* __restrict__ csr, unsigned int* __restrict__ rowinfo) {
    const int b = blockIdx.x;
    int N, dstBase, infoBase;
    if (b < nbV)          { N = Nvar; dstBase = b * 256;             infoBase = 0; }
    else if (b < 2 * nbV) { N = Nvar; dstBase = (b - nbV) * 256;     infoBase = Nvar; }
    else                  { N = Ncon; dstBase = (b - 2 * nbV) * 256; infoBase = 2 * Nvar; }

    __shared__ int hist[256], scan[256], cur[256];
    const int t = threadIdx.x;
    const long segBase = ((long)t * totBins + b) * CAP_SEG;   // thread t's segment of this bin
    const int sc = segcnt[(long)t * totBins + b];

    hist[t] = 0;
    __syncthreads();
    for (int i = 0; i < sc; ++i) atomicAdd(&hist[pairs[segBase + i] & 255], 1);
    __syncthreads();
    scan[t] = hist[t];
    __syncthreads();
    for (int off = 1; off < 256; off <<= 1) {
        int u = (t >= off) ? scan[t - off] : 0;
        __syncthreads();
        scan[t] += u;
        __syncthreads();
    }
    const int excl = scan[t] - hist[t];
    cur[t] = excl;
    if (dstBase + t < N)
        rowinfo[infoBase + dstBase + t] = ((unsigned int)excl << 16) | (unsigned int)hist[t];
    __syncthreads();
    for (int i = 0; i < sc; ++i) {
        unsigned int pr = pairs[segBase + i];
        int slot = atomicAdd(&cur[pr & 255], 1);   // LDS atomic
        csr[(long)b * CSRB + slot] = pr >> 8;      // src index; slot < SEGS*CAP_SEG = CSRB always
    }
}

// ---------------- pass 3: pull-aggregate from CSR — 4 dst rows per wave ----------------
__launch_bounds__(256)
__global__ void pull_csr3(int Nvar, int Ncon, int nbV,
                          const unsigned short* __restrict__ xv, const unsigned short* __restrict__ xr,
                          const unsigned int* __restrict__ csr, const unsigned int* __restrict__ rowinfo,
                          const int* __restrict__ s0, const int* __restrict__ d0, const int* __restrict__ o0,
                          const int* __restrict__ s1, const int* __restrict__ d1, const int* __restrict__ o1,
                          const int* __restrict__ s2, const int* __restrict__ d2, const int* __restrict__ o2,
                          const int* __restrict__ ovf_cnt,
                          unsigned short* __restrict__ agg_adj, unsigned short* __restrict__ agg_g,
                          unsigned short* __restrict__ agg_t) {
    const int tx = threadIdx.x;
    const int lane = tx & 63;
    const int ql = lane & 15;            // column group: cols [ql*8 .. ql*8+7]
    const int sl = lane & 48;            // quarter base lane (q*16)
    const long colOff = (long)ql * 8;

    const long tot = 2L * Nvar + Ncon;
    const long wv = ((long)blockIdx.x * blockDim.x + tx) >> 6;
    long r = wv * 4 + (lane >> 4);       // this quarter's dst row (global id)
    const bool active = r < tot;
    if (!active) r = tot - 1;            // clamp for safe addressing; store guarded

    // per-lane graph selection (uniform within quarter)
    const bool g1 = (r >= Nvar) && (r < 2L * Nvar);
    const bool g2 = (r >= 2L * Nvar);
    const unsigned short* y = g1 ? xr : xv;
    const int wid = (int)(r - (g1 ? (long)Nvar : 0) - (g2 ? 2L * Nvar : 0));
    const int infoBase = g1 ? Nvar : (g2 ? 2 * Nvar : 0);
    const long binBase = g1 ? nbV : (g2 ? 2L * nbV : 0);
    unsigned short* agg = g1 ? agg_g : (g2 ? agg_t : agg_adj);

    const unsigned int info = rowinfo[infoBase + wid];
    const int mc = active ? (int)(info & 0xffffu) : 0;
    const long b = binBase + (wid >> 8);
    const long cbase = b * CSRB + (long)(info >> 16);

    float a0 = 0.f, a1 = 0.f, a2 = 0.f, a3 = 0.f, a4 = 0.f, a5 = 0.f, a6 = 0.f, a7 = 0.f;

    for (int base = 0; __any(base < mc); base += 16) {
        int idx = (base + ql < mc) ? (int)csr[cbase + base + ql] : 0;
        for (int jj = 0; jj < 16; jj += 4) {
            const int e = base + jj;
            if (!__any(e < mc)) break;
            int i0 = __shfl(idx, sl + jj + 0, 64);   // edge e of OWN quarter's row
            int i1 = __shfl(idx, sl + jj + 1, 64);
            int i2 = __shfl(idx, sl + jj + 2, 64);
            int i3 = __shfl(idx, sl + jj + 3, 64);
            uint4 r0 = *(const uint4*)(y + (long)i0 * D + colOff);
            uint4 r1 = *(const uint4*)(y + (long)i1 * D + colOff);
            uint4 r2 = *(const uint4*)(y + (long)i2 * D + colOff);
            uint4 r3 = *(const uint4*)(y + (long)i3 * D + colOff);
            unsigned int w01 = ((e     < mc) ? 0x3F80u : 0u) | ((e + 1 < mc) ? 0x3F800000u : 0u);
            unsigned int w23 = ((e + 2 < mc) ? 0x3F80u : 0u) | ((e + 3 < mc) ? 0x3F800000u : 0u);
            unsigned int p;
            // perm 0x01000504: (src0.lo_bf16, src1.lo_bf16); 0x03020706: high halves
            p = __builtin_amdgcn_perm(r0.x, r1.x, 0x01000504u); dot2bf(a0, p, w01);
            p = __builtin_amdgcn_perm(r2.x, r3.x, 0x01000504u); dot2bf(a0, p, w23);
            p = __builtin_amdgcn_perm(r0.x, r1.x, 0x03020706u); dot2bf(a1, p, w01);
            p = __builtin_amdgcn_perm(r2.x, r3.x, 0x03020706u); dot2bf(a1, p, w23);
            p = __builtin_amdgcn_perm(r0.y, r1.y, 0x01000504u); dot2bf(a2, p, w01);
            p = __builtin_amdgcn_perm(r2.y, r3.y, 0x01000504u); dot2bf(a2, p, w23);
            p = __builtin_amdgcn_perm(r0.y, r1.y, 0x03020706u); dot2bf(a3, p, w01);
            p = __builtin_amdgcn_perm(r2.y, r3.y, 0x03020706u); dot2bf(a3, p, w23);
            p = __builtin_amdgcn_perm(r0.z, r1.z, 0x01000504u); dot2bf(a4, p, w01);
            p = __builtin_amdgcn_perm(r2.z, r3.z, 0x01000504u); dot2bf(a4, p, w23);
            p = __builtin_amdgcn_perm(r0.z, r1.z, 0x03020706u); dot2bf(a5, p, w01);
            p = __builtin_amdgcn_perm(r2.z, r3.z, 0x03020706u); dot2bf(a5, p, w23);
            p = __builtin_amdgcn_perm(r0.w, r1.w, 0x01000504u); dot2bf(a6, p, w01);
            p = __builtin_amdgcn_perm(r2.w, r3.w, 0x01000504u); dot2bf(a6, p, w23);
            p = __builtin_amdgcn_perm(r0.w, r1.w, 0x03020706u); dot2bf(a7, p, w01);
            p = __builtin_amdgcn_perm(r2.w, r3.w, 0x03020706u); dot2bf(a7, p, w23);
        }
    }

    // rare exact fallback: only if some edge of this graph overflowed its segment
    const int oc = ovf_cnt[g1 ? 16 : (g2 ? 32 : 0)];
    if (active && oc > 0) {
        const int* srcp = g1 ? s1 : (g2 ? s2 : s0);
        const int* dstp = g1 ? d1 : (g2 ? d2 : d0);
        const int* ovf  = g1 ? o1 : (g2 ? o2 : o0);
        for (int i = 0; i < oc; ++i) {
            int e = ovf[i];
            if (dstp[e] == wid) {        // every lane of the quarter adds its own cols
                int s = srcp[e];
                uint4 rr = *(const uint4*)(y + (long)s * D + colOff);
                a0 += bf2f(rr.x & 0xffffu); a1 += bf2f(rr.x >> 16);
                a2 += bf2f(rr.y & 0xffffu); a3 += bf2f(rr.y >> 16);
                a4 += bf2f(rr.z & 0xffffu); a5 += bf2f(rr.z >> 16);
                a6 += bf2f(rr.w & 0xffffu); a7 += bf2f(rr.w >> 16);
            }
        }
    }

    if (active) {
        uint4 o;
        o.x = pk_bf16(a0, a1);
        o.y = pk_bf16(a2, a3);
        o.z = pk_bf16(a4, a5);
        o.w = pk_bf16(a6, a7);
        *(uint4*)(agg + (long)wid * D + colOff) = o;
    }
}

// ---------------- fused MFMA GEMM, LDS-staged (m97-style 2-phase) ----------------
// SPLIT var/con dispatches REQUIRED: merging (R4, R12) doubles HBM traffic (+66us).
// __syncthreads() K-loop ONLY (see header comment: raw-barrier variant races, R15).
// Epilogue: sstat aliases lds[0] (dead after final barrier) -> 32KB LDS block ->
// 5 blocks/CU; quad-reduce -> 1 lane/address/wave on sstat atomics.
__launch_bounds__(256, 5)
__global__ void gemm_fused(int N,
                           const unsigned short* __restrict__ A0, const unsigned short* __restrict__ Wt0,
                           const unsigned short* __restrict__ A1, const unsigned short* __restrict__ Wt1,
                           const unsigned short* __restrict__ A2, const unsigned short* __restrict__ Wt2,
                           int nTerms,
                           const float* __restrict__ bias, float* __restrict__ out,
                           float* __restrict__ gsum, float* __restrict__ gsq) {
    __shared__ unsigned short lds[2][8192];   // per buf: A slots 0..511 (8KB), B slots at +4096 (8KB)
    const int tx = threadIdx.x;

    const int wave = tx >> 6, lane = tx & 63;
    const int quad = lane >> 4, l16 = lane & 15;
    const int row0 = blockIdx.x * 128;

    const int sA0 = tx, sA1 = tx + 256;
    const int rS0 = sA0 >> 2, qS0 = (sA0 & 3) ^ ((sA0 >> 4) & 3);
    const int rS1 = sA1 >> 2, qS1 = (sA1 & 3) ^ ((sA1 >> 4) & 3);
    long gr0 = (long)row0 + rS0; if (gr0 >= N) gr0 = N - 1;
    long gr1 = (long)row0 + rS1; if (gr1 >= N) gr1 = N - 1;

    f32x4 acc[2][8];
#pragma unroll
    for (int rt = 0; rt < 2; ++rt)
#pragma unroll
        for (int ct = 0; ct < 8; ++ct)
#pragma unroll
            for (int i = 0; i < 4; ++i) acc[rt][ct][i] = 0.f;

    auto stage = [&](int s, int bb) {
        const int t = s >> 2;
        const int k0 = (s & 3) * 32;
        const unsigned short* A = (t == 0) ? A0 : ((t == 1) ? A1 : A2);
        const unsigned short* W = (t == 0) ? Wt0 : ((t == 1) ? Wt1 : Wt2);
        __builtin_amdgcn_global_load_lds(
            (const __attribute__((address_space(1))) unsigned int*)(A + gr0 * D + k0 + qS0 * 8),
            (__attribute__((address_space(3))) unsigned int*)(&lds[bb][sA0 * 8]), 16, 0, 0);
        __builtin_amdgcn_global_load_lds(
            (const __attribute__((address_space(1))) unsigned int*)(A + gr1 * D + k0 + qS1 * 8),
            (__attribute__((address_space(3))) unsigned int*)(&lds[bb][sA1 * 8]), 16, 0, 0);
        __builtin_amdgcn_global_load_lds(
            (const __attribute__((address_space(1))) unsigned int*)(W + (long)rS0 * D + k0 + qS0 * 8),
            (__attribute__((address_space(3))) unsigned int*)(&lds[bb][4096 + sA0 * 8]), 16, 0, 0);
        __builtin_amdgcn_global_load_lds(
            (const __attribute__((address_space(1))) unsigned int*)(W + (long)rS1 * D + k0 + qS1 * 8),
            (__attribute__((address_space(3))) unsigned int*)(&lds[bb][4096 + sA1 * 8]), 16, 0, 0);
    };

    const int xq = (l16 >> 2) & 3;
    const int qx = quad ^ xq;

    auto compute = [&](int cb) {
        const int slotA0 = (wave * 32 + l16) * 4 + qx;
        const int slotA1 = (wave * 32 + 16 + l16) * 4 + qx;
        bf16x8 a0 = *(const bf16x8*)&lds[cb][slotA0 * 8];
        bf16x8 a1 = *(const bf16x8*)&lds[cb][slotA1 * 8];
#pragma unroll
        for (int ct = 0; ct < 8; ++ct) {
            const int slotB = (ct * 16 + l16) * 4 + qx;
            bf16x8 b = *(const bf16x8*)&lds[cb][4096 + slotB * 8];
            acc[0][ct] = __builtin_amdgcn_mfma_f32_16x16x32_bf16(a0, b, acc[0][ct], 0, 0, 0);
            acc[1][ct] = __builtin_amdgcn_mfma_f32_16x16x32_bf16(a1, b, acc[1][ct], 0, 0, 0);
        }
    };

    const int nsteps = nTerms * 4;
    stage(0, 0);
    __syncthreads();
    for (int s = 0; s < nsteps; ++s) {
        const int cb = s & 1;
        if (s + 1 < nsteps) stage(s + 1, cb ^ 1);
        compute(cb);
        __syncthreads();                  // last iteration: all waves done reading LDS -> safe to alias
    }

    // epilogue: bias, store, per-column partial stats
    float bv[8];
#pragma unroll
    for (int ct = 0; ct < 8; ++ct) bv[ct] = bias[ct * 16 + l16];

    float psum[8], psq[8];
#pragma unroll
    for (int ct = 0; ct < 8; ++ct) { psum[ct] = 0.f; psq[ct] = 0.f; }

#pragma unroll
    for (int rt = 0; rt < 2; ++rt)
#pragma unroll
        for (int i = 0; i < 4; ++i) {
            int row = row0 + wave * 32 + rt * 16 + quad * 4 + i;
            if (row < N) {
#pragma unroll
                for (int ct = 0; ct < 8; ++ct) {
                    float v = acc[rt][ct][i] + bv[ct];
                    out[(size_t)row * D + ct * 16 + l16] = v;
                    psum[ct] += v;
                    psq[ct] += v * v;
                }
            }
        }

    // quad-reduce: lanes {l16, l16+16, l16+32, l16+48} hold the same column ct*16+l16
#pragma unroll
    for (int ct = 0; ct < 8; ++ct) {
        psum[ct] += __shfl_xor(psum[ct], 16, 64);
        psum[ct] += __shfl_xor(psum[ct], 32, 64);
        psq[ct]  += __shfl_xor(psq[ct], 16, 64);
        psq[ct]  += __shfl_xor(psq[ct], 32, 64);
    }

    // block stats staging reuses lds (K-loop data dead)
    float* sstat = (float*)&lds[0][0];
    sstat[tx] = 0.f;
    __syncthreads();
    if (quad == 0) {
#pragma unroll
        for (int ct = 0; ct < 8; ++ct) {
            atomicAdd(&sstat[ct * 16 + l16], psum[ct]);
            atomicAdd(&sstat[128 + ct * 16 + l16], psq[ct]);
        }
    }
    __syncthreads();
    if (tx < 128) {
        atomAddF(&gsum[tx], sstat[tx]);
        atomAddF(&gsq[tx], sstat[128 + tx]);
    }
}

// ---------------- fused normalize+relu with per-block stats finalization ----------------
__global__ void norm_relu_fin(float* __restrict__ buf,
                              long nvecVar, long nvecTot,
                              const float* __restrict__ stats,
                              const float* __restrict__ wv, const float* __restrict__ bv, const float* __restrict__ msv,
                              const float* __restrict__ wc, const float* __restrict__ bc, const float* __restrict__ msc,
                              int Nvar, int Ncon) {
    __shared__ float ss[512];   // [0:128) scale_var [128:256) shift_var [256:384) scale_con [384:512) shift_con
    const int t = threadIdx.x;
    {
        const int col = t & 127;
        const bool isv = t < 128;
        const float n = isv ? (float)Nvar : (float)Ncon;
        const float* st = stats + (isv ? 0 : 256);
        const float mu = st[col] / n;
        const float ex2 = st[128 + col] / n;
        const float ms = (isv ? msv : msc)[col];
        const float var = ex2 - 2.f * ms * mu * mu + ms * ms * mu * mu;
        const float istd = rsqrtf(var + 1e-5f);
        const float sc = (isv ? wv : wc)[col] * istd;
        ss[(isv ? 0 : 256) + col] = sc;
        ss[(isv ? 128 : 384) + col] = (isv ? bv : bc)[col] - sc * ms * mu;
    }
    __syncthreads();
    long i = (long)blockIdx.x * blockDim.x + t;
    if (i >= nvecTot) return;
    const int base = (i < nvecVar) ? 0 : 256;
    const int q = ((int)i & 31) * 4;
    float4 v = *(float4*)(buf + i * 4);
    float4 o;
    o.x = fmaxf(0.f, v.x * ss[base + q + 0] + ss[base + 128 + q + 0]);
    o.y = fmaxf(0.f, v.y * ss[base + q + 1] + ss[base + 128 + q + 1]);
    o.z = fmaxf(0.f, v.z * ss[base + q + 2] + ss[base + 128 + q + 2]);
    o.w = fmaxf(0.f, v.w * ss[base + q + 3] + ss[base + 128 + q + 3]);
    *(float4*)(buf + i * 4) = o;
}

extern "C" void kernel_launch(void* const* d_in, const int* in_sizes, int n_in,
                              void* d_out, int out_size, void* d_ws, size_t ws_size,
                              hipStream_t stream) {
    const float* x_var = (const float*)d_in[0];
    const float* x_con = (const float*)d_in[1];
    const float* x_reg = (const float*)d_in[2];
    const int* src_adj = (const int*)d_in[3];
    const int* dst_adj = (const int*)d_in[4];
    const int* src_t   = (const int*)d_in[5];
    const int* dst_t   = (const int*)d_in[6];
    const int* src_g   = (const int*)d_in[7];
    const int* dst_g   = (const int*)d_in[8];
    const float* W_rel_adj  = (const float*)d_in[9];
    const float* b_adj      = (const float*)d_in[10];
    const float* W_root_adj = (const float*)d_in[11];
    const float* W_rel_t    = (const float*)d_in[12];
    const float* b_t        = (const float*)d_in[13];
    const float* W_root_t   = (const float*)d_in[14];
    const float* W_rel_g    = (const float*)d_in[15];
    const float* b_g        = (const float*)d_in[16];
    const float* W_root_g   = (const float*)d_in[17];
    const float* gnw_v  = (const float*)d_in[18];
    const float* gnb_v  = (const float*)d_in[19];
    const float* gnms_v = (const float*)d_in[20];
    const float* gnw_c  = (const float*)d_in[21];
    const float* gnb_c  = (const float*)d_in[22];
    const float* gnms_c = (const float*)d_in[23];

    const int Nvar = in_sizes[0] / D;
    const int Ncon = in_sizes[1] / D;
    const int Nreg = in_sizes[2] / D;
    const int Eadj = in_sizes[3];
    const int Et   = in_sizes[5];
    const int Eg   = in_sizes[7];

    const int nbV = (Nvar + 255) >> 8;     // bins per var-dst graph (adj, groups)
    const int nbC = (Ncon + 255) >> 8;     // bins for touch
    const int totBins = 2 * nbV + nbC;

    // ---- workspace layout (large blocks first, all 256B-aligned) ----
    char* p = (char*)d_ws;
    unsigned short* xv_bf = (unsigned short*)p; p += (size_t)Nvar * D * 2;
    unsigned short* xc_bf = (unsigned short*)p; p += (size_t)Ncon * D * 2;
    unsigned short* xr_bf = (unsigned short*)p; p += (size_t)Nreg * D * 2;
    unsigned short* agg_adj = (unsigned short*)p; p += (size_t)Nvar * D * 2;
    unsigned short* agg_g   = (unsigned short*)p; p += (size_t)Nvar * D * 2;
    unsigned short* agg_t   = (unsigned short*)p; p += (size_t)Ncon * D * 2;
    unsigned int* pairs = (unsigned int*)p; p += (size_t)SEGS * totBins * CAP_SEG * 4;
    unsigned int* csr   = (unsigned int*)p; p += (size_t)totBins * CSRB * 4;
    int* segcnt = (int*)p; p += (size_t)SEGS * totBins * 4;
    unsigned int* rowinfo = (unsigned int*)p; p += (size_t)(2 * Nvar + Ncon) * 4;
    int* ovf0 = (int*)p; p += (size_t)Eadj * 4;
    int* ovf1 = (int*)p; p += (size_t)Eg * 4;
    int* ovf2 = (int*)p; p += (size_t)Et * 4;
    unsigned short* Wt_adj    = (unsigned short*)p; p += D * D * 2;
    unsigned short* Wt_g      = (unsigned short*)p; p += D * D * 2;
    unsigned short* Wt_t      = (unsigned short*)p; p += D * D * 2;
    unsigned short* Wt_root_t = (unsigned short*)p; p += D * D * 2;
    unsigned short* Wt_sum    = (unsigned short*)p; p += D * D * 2;
    float* bsum  = (float*)p; p += D * 4;
    // ---- contiguous zero region: stats(512f) + ovf_cnt(64i) ----
    char* zbase = p;
    float* stats   = (float*)p; p += 512 * 4;
    int* ovf_cnt   = (int*)p;   p += 64 * 4;         // [0],[16],[32] used
    const long zwords = (long)(p - zbase) / 4;

    float* out_var = (float*)d_out;
    float* out_con = out_var + (size_t)Nvar * D;

    // 1: fused weights-prep + zero + casts
    {
        long n4v = (long)Nvar * 32, n4c = (long)Ncon * 32, n4r = (long)Nreg * 32;
        long tot = (long)D * D + zwords + n4v + n4c + n4r;
        prep_cast_zero<<<(int)((tot + 255) / 256), 256, 0, stream>>>(
            W_rel_adj, W_rel_g, W_rel_t, W_root_t, W_root_adj, W_root_g, b_adj, b_g,
            Wt_adj, Wt_g, Wt_t, Wt_root_t, Wt_sum, bsum,
            (unsigned int*)zbase, zwords,
            x_var, n4v, x_con, n4c, x_reg, n4r, xv_bf, xc_bf, xr_bf);
    }

    // 2: single-pass private-segment binning, tile-interleaved (grid MUST be SEGS)
    binscatter3<<<SEGS, 256, 0, stream>>>(
        src_adj, dst_adj, Eadj,
        src_g,   dst_g,   Eg,
        src_t,   dst_t,   Et,
        nbV, totBins, pairs, segcnt, ovf0, ovf1, ovf2, ovf_cnt);

    // 3: per-bin CSR build (blockDim MUST be SEGS)
    build_csr<<<totBins, SEGS, 0, stream>>>(nbV, Nvar, Ncon, totBins, pairs, segcnt, csr, rowinfo);

    // 4: pull-aggregate from CSR (4 rows per wave)
    {
        long rows = (long)2 * Nvar + Ncon;
        long T = ((rows + 3) / 4) * 64;
        pull_csr3<<<(int)((T + 255) / 256), 256, 0, stream>>>(
            Nvar, Ncon, nbV, xv_bf, xr_bf,
            csr, rowinfo,
            src_adj, dst_adj, ovf0,
            src_g,   dst_g,   ovf1,
            src_t,   dst_t,   ovf2,
            ovf_cnt, agg_adj, agg_g, agg_t);
    }

    // 5,6: GEMMs — SPLIT dispatches (merge doubles HBM traffic; see gemm_fused comment)
    gemm_fused<<<(Nvar + 127) / 128, 256, 0, stream>>>(Nvar,
        agg_adj, Wt_adj, agg_g, Wt_g, xv_bf, Wt_sum, 3,
        bsum, out_var, stats, stats + 128);
    gemm_fused<<<(Ncon + 127) / 128, 256, 0, stream>>>(Ncon,
        agg_t, Wt_t, xc_bf, Wt_root_t, nullptr, nullptr, 2,
        b_t, out_con, stats + 256, stats + 384);

    // 7: fused normalize+relu+finalize over the contiguous [out_var | out_con] buffer
    {
        long nvecVar = (long)Nvar * 32;
        long nvecTot = (long)(Nvar + Ncon) * 32;
        norm_relu_fin<<<(int)((nvecTot + 255) / 256), 256, 0, stream>>>(
            out_var, nvecVar, nvecTot, stats,
            gnw_v, gnb_v, gnms_v, gnw_c, gnb_c, gnms_c, Nvar, Ncon);
    }
}